// Round 11
// baseline (239.908 us; speedup 1.0000x reference)
//
#include <hip/hip_runtime.h>
#include <math.h>

#define B_ 16
#define C_ 512
#define H_ 56
#define W_ 56
#define N_ 3136          // H_*W_ = 49*64
#define NH 8
#define HD 64
#define SPLIT 7          // n-split for gram; 3136/7 = 448
#define ICPB 4           // conv channels per block

typedef unsigned short bf16;
typedef __attribute__((ext_vector_type(8))) short short8;
typedef __attribute__((ext_vector_type(4))) float f32x4;

__device__ inline float bf2f(unsigned short u) {
    union { unsigned int i; float f; } v; v.i = ((unsigned int)u) << 16; return v.f;
}
__device__ inline unsigned short f2bf(float f) {
    union { float f; unsigned int i; } v; v.f = f;
    unsigned int r = v.i + 0x7fffu + ((v.i >> 16) & 1u);
    return (unsigned short)(r >> 16);
}

// async global->LDS, 16B per lane, linear dest (wave-uniform base + lane*16)
__device__ inline void load_lds16(const void* g, void* l) {
    __builtin_amdgcn_global_load_lds(
        (const __attribute__((address_space(1))) void*)g,
        (__attribute__((address_space(3))) void*)l, 16, 0, 0);
}

// ---------------------------------------------------------------------------
// Depthwise 3x3 conv + BN. Block = (b_l, 4-channel group); per-ic consts are
// block-uniform scalars. Thread t < 392 owns one 8-wide pixel group; loop over
// the 4 channels gives ILP (independent load/compute chains) to cover latency.
// ---------------------------------------------------------------------------
__global__ __launch_bounds__(448) void conv_bn_kernel(
    const float* __restrict__ x, const float* __restrict__ cw,
    const float* __restrict__ gamma, const float* __restrict__ beta,
    const float* __restrict__ mean, const float* __restrict__ var,
    bf16* __restrict__ qkdst, bf16* __restrict__ vdst, int b0)
{
    int bid = blockIdx.x;                 // nb * (C_/ICPB)
    int icg = bid & 127; int b_l = bid >> 7;
    int b = b0 + b_l;
    int t = threadIdx.x;
    if (t >= 392) return;
    int yy = t / 7;
    int xx0 = (t - yy * 7) * 8;
    int n0 = t * 8;                       // == yy*56 + xx0

    for (int ii = 0; ii < ICPB; ++ii) {
        int ic = icg * ICPB + ii;
        const float* xin = x + ((size_t)b * C_ + ic) * N_;
        float w9[3][9], inv3[3], bias3[3];
#pragma unroll
        for (int ft = 0; ft < 3; ++ft) {
            int o = ic * 3 + ft;
#pragma unroll
            for (int k = 0; k < 9; ++k) w9[ft][k] = cw[o * 9 + k];
            float iv = gamma[o] * rsqrtf(var[o] + 1e-5f);
            inv3[ft] = iv;
            bias3[ft] = fmaf(-mean[o], iv, beta[o]);
        }
        float vin[3][10];
#pragma unroll
        for (int dy = 0; dy < 3; ++dy) {
            int y2 = yy + dy - 1;
            bool rowok = (y2 >= 0) && (y2 < H_);
            const float* rp = xin + y2 * W_ + xx0;
            if (rowok) {
                float4 a = *(const float4*)rp;
                float4 c4 = *(const float4*)(rp + 4);
                vin[dy][1] = a.x;  vin[dy][2] = a.y;  vin[dy][3] = a.z;  vin[dy][4] = a.w;
                vin[dy][5] = c4.x; vin[dy][6] = c4.y; vin[dy][7] = c4.z; vin[dy][8] = c4.w;
                vin[dy][0] = (xx0 > 0)  ? rp[-1] : 0.f;
                vin[dy][9] = (xx0 < 48) ? rp[8]  : 0.f;
            } else {
#pragma unroll
                for (int j = 0; j < 10; ++j) vin[dy][j] = 0.f;
            }
        }
#pragma unroll
        for (int ft = 0; ft < 3; ++ft) {
            int o = ic * 3 + ft;          // uniform
            int s = o >> 9;               // uniform
            int c = o & 511;
            short8 r8;
#pragma unroll
            for (int j = 0; j < 8; ++j) {
                float acc = 0.f;
#pragma unroll
                for (int ky = 0; ky < 3; ++ky)
#pragma unroll
                    for (int kx = 0; kx < 3; ++kx)
                        acc = fmaf(vin[ky][j + kx], w9[ft][ky*3+kx], acc);
                r8[j] = (short)f2bf(fmaf(acc, inv3[ft], bias3[ft]));
            }
            bf16* dst = (s < 2)
                ? qkdst + (((size_t)b_l * 2 + s) * C_ + c) * N_
                : vdst + ((size_t)b_l * C_ + c) * N_;
            *(short8*)(dst + n0) = r8;
        }
    }
}

// ---------------------------------------------------------------------------
// Gram partials via MFMA (T2 swizzle + gload_lds):
//   part[s][bh][d*64+e] = sum_{n in split s} q[d,n]*k[e,n]
// ---------------------------------------------------------------------------
__global__ __launch_bounds__(256) void gram_mfma_kernel(
    const bf16* __restrict__ qk, float* __restrict__ part, int bhTot)
{
    __shared__ bf16 qs[64 * 64];
    __shared__ bf16 ks[64 * 64];
    int bid = blockIdx.x;                 // bhTot*SPLIT
    int s = bid % SPLIT; int bh = bid / SPLIT;
    int h = bh % NH; int b_l = bh / NH;
    const bf16* qp = qk + (((size_t)b_l * 2 + 0) * C_ + h * HD) * N_;
    const bf16* kp = qk + (((size_t)b_l * 2 + 1) * C_ + h * HD) * N_;
    int t = threadIdx.x;
    int w = t >> 6, l = t & 63;
    int r16 = l & 15, kg = l >> 4;
    int wr = w >> 1, wc = w & 1;
    int rsub = l >> 3;
    int colp = ((l & 7) ^ rsub) * 8;      // pre-swizzled n-element offset
    int n0 = s * (N_ / SPLIT);

    f32x4 acc[2][2];
#pragma unroll
    for (int i = 0; i < 2; ++i)
#pragma unroll
        for (int j = 0; j < 2; ++j) acc[i][j] = (f32x4){0.f, 0.f, 0.f, 0.f};

    for (int nc = 0; nc < N_ / SPLIT; nc += 64) {
        int nb = n0 + nc;
#pragma unroll
        for (int i = 0; i < 2; ++i) {
            int row = i * 32 + w * 8 + rsub;
            load_lds16(qp + (size_t)row * N_ + nb + colp, (char*)qs + i * 4096 + t * 16);
            load_lds16(kp + (size_t)row * N_ + nb + colp, (char*)ks + i * 4096 + t * 16);
        }
        __syncthreads();
#pragma unroll
        for (int ksb = 0; ksb < 2; ++ksb) {
            short8 af[2], bfv[2];
#pragma unroll
            for (int mi = 0; mi < 2; ++mi) {
                int row = wr * 32 + mi * 16 + r16;
                int off = row * 128 + ((ksb * 64 + kg * 16) ^ ((row & 7) << 4));
                af[mi] = *(const short8*)((const char*)qs + off);
            }
#pragma unroll
            for (int nj = 0; nj < 2; ++nj) {
                int row = wc * 32 + nj * 16 + r16;
                int off = row * 128 + ((ksb * 64 + kg * 16) ^ ((row & 7) << 4));
                bfv[nj] = *(const short8*)((const char*)ks + off);
            }
#pragma unroll
            for (int mi = 0; mi < 2; ++mi)
#pragma unroll
                for (int nj = 0; nj < 2; ++nj)
                    acc[mi][nj] = __builtin_amdgcn_mfma_f32_16x16x32_bf16(
                        af[mi], bfv[nj], acc[mi][nj], 0, 0, 0);
        }
        __syncthreads();
    }
    float* pp = part + ((size_t)s * bhTot + bh) * 4096;
#pragma unroll
    for (int mi = 0; mi < 2; ++mi)
#pragma unroll
        for (int nj = 0; nj < 2; ++nj) {
            int e = wc * 32 + nj * 16 + r16;
#pragma unroll
            for (int r = 0; r < 4; ++r) {
                int d = wr * 32 + mi * 16 + kg * 4 + r;
                pp[d * 64 + e] = acc[mi][nj][r];
            }
        }
}

// ---------------------------------------------------------------------------
// Reduce partials, scale, softmax over e. One wave per (bh,d) row.
// Writes P TRANSPOSED: PT[bh][e*64+d].
// ---------------------------------------------------------------------------
__global__ __launch_bounds__(64) void softmax_kernel(
    const float* __restrict__ part, float* __restrict__ PT, int bhTot)
{
    int row = blockIdx.x;                 // bh*64 + d
    int e = threadIdx.x;
    size_t base = (size_t)row * 64 + e;
    float val = 0.f;
#pragma unroll
    for (int s = 0; s < SPLIT; ++s) val += part[(size_t)s * bhTot * 4096 + base];
    val *= 0.125f;                        // hd^-0.5
    float m = val;
#pragma unroll
    for (int off = 32; off > 0; off >>= 1) m = fmaxf(m, __shfl_xor(m, off));
    float ex = expf(val - m);
    float sum = ex;
#pragma unroll
    for (int off = 32; off > 0; off >>= 1) sum += __shfl_xor(sum, off);
    PT[(size_t)(row >> 6) * 4096 + (size_t)e * 64 + (row & 63)] = ex / sum;
}

// ---------------------------------------------------------------------------
// outA[b_l][d][h][n] = sum_e PT[e][d] * v[b_l][h*64+e][n]   (bf16 out)
// Block = (bh, 1/7 of n): PT staged ONCE (16KB), 7 v-tiles double-buffered.
// ---------------------------------------------------------------------------
__global__ __launch_bounds__(256) void pv_kernel(
    const bf16* __restrict__ v, const float* __restrict__ PT,
    bf16* __restrict__ outA)
{
    __shared__ float pts[4096];           // PT[e][d] 16KB
    __shared__ bf16 vs[2][4096];          // vs[buf][e][n] 2x8KB
    int bid = blockIdx.x;                 // bhTot*7
    int seg = bid % 7; int bh = bid / 7;
    int h = bh % NH, b_l = bh / NH;
    int t = threadIdx.x;
    const float* ptg = PT + (size_t)bh * 4096;
#pragma unroll
    for (int i = 0; i < 4; ++i)
        load_lds16(ptg + i * 1024 + t * 4, (char*)pts + i * 4096 + t * 16);
    const bf16* vbase = v + ((size_t)b_l * C_ + h * HD) * N_ + seg * 448;
#pragma unroll
    for (int i = 0; i < 2; ++i) {
        int row = i * 32 + (t >> 3);
        load_lds16(vbase + (size_t)row * N_ + (t & 7) * 8,
                   (char*)vs[0] + i * 4096 + t * 16);
    }
    __syncthreads();

    int ng = t & 15, dg = t >> 4;         // n-sub = ng*4, d0 = dg*4
    int cur = 0;
    bf16* opbase = outA + (size_t)b_l * (C_*N_) + (size_t)h * N_ + seg * 448 + ng * 4;
    for (int ti = 0; ti < 7; ++ti) {
        if (ti < 6) {
#pragma unroll
            for (int i = 0; i < 2; ++i) {
                int row = i * 32 + (t >> 3);
                load_lds16(vbase + (ti + 1) * 64 + (size_t)row * N_ + (t & 7) * 8,
                           (char*)vs[cur ^ 1] + i * 4096 + t * 16);
            }
        }
        float acc[4][4] = {};
#pragma unroll 16
        for (int e = 0; e < 64; ++e) {
            float4 p = *(const float4*)&pts[e * 64 + dg * 4];
            ushort4 vv = *(const ushort4*)&vs[cur][e * 64 + ng * 4];
            float v0 = bf2f(vv.x), v1 = bf2f(vv.y), v2 = bf2f(vv.z), v3 = bf2f(vv.w);
            float p4[4] = {p.x, p.y, p.z, p.w};
#pragma unroll
            for (int i = 0; i < 4; ++i) {
                acc[i][0] = fmaf(p4[i], v0, acc[i][0]);
                acc[i][1] = fmaf(p4[i], v1, acc[i][1]);
                acc[i][2] = fmaf(p4[i], v2, acc[i][2]);
                acc[i][3] = fmaf(p4[i], v3, acc[i][3]);
            }
        }
        bf16* op = opbase + ti * 64;
#pragma unroll
        for (int i = 0; i < 4; ++i) {
            ushort4 r4;
            unsigned short* rr = (unsigned short*)&r4;
            rr[0] = f2bf(acc[i][0]); rr[1] = f2bf(acc[i][1]);
            rr[2] = f2bf(acc[i][2]); rr[3] = f2bf(acc[i][3]);
            *(ushort4*)(op + (size_t)(dg * 4 + i) * (NH*N_)) = r4;
        }
        __syncthreads();                  // drain stage + protect vs[cur]
        cur ^= 1;
    }
}

// ---------------------------------------------------------------------------
// Convert projection weights f32 -> bf16 (512x512).
// ---------------------------------------------------------------------------
__global__ __launch_bounds__(256) void wconv_kernel(
    const float* __restrict__ w, bf16* __restrict__ wb)
{
    int i = blockIdx.x * 256 + threadIdx.x;   // 262144 total
    wb[i] = f2bf(w[i]);
}

// ---------------------------------------------------------------------------
// MFMA projection, 2-phase double-buffered + XCD-chunked swizzle:
//   out[b0+b_l][co][n] = sum_c Wb[co][c]*A[b_l][n][c] + pb[co]
// ---------------------------------------------------------------------------
__global__ __launch_bounds__(256) void proj_mfma_kernel(
    const bf16* __restrict__ A, const bf16* __restrict__ Wb,
    const float* __restrict__ bias, float* __restrict__ out, int b0, int nwg)
{
    __shared__ bf16 Ws_s[2][128 * 64];
    __shared__ bf16 As_s[2][128 * 64];
    int bid = blockIdx.x;                 // nwg = nb*100, nwg % 8 == 0
    int cpx = nwg >> 3;                   // chunk per XCD (200: % 4 == 0)
    int swz = (bid & 7) * cpx + (bid >> 3);
    int b_l = swz / 100; int rem = swz % 100;
    int nt = rem >> 2, mt = rem & 3;      // mt fastest: A-quad on one XCD
    int m0 = mt * 128, n0 = nt * 128;
    int t = threadIdx.x;
    int w = t >> 6, l = t & 63;
    int r16 = l & 15, kg = l >> 4;        // frag row / k-group
    int wr = w >> 1, wc = w & 1;          // wave quadrant
    const bf16* Ab = A + (size_t)b_l * N_ * C_;
    int rsub = l >> 3;                    // row within the 8-row wave chunk
    int colp = ((l & 7) ^ rsub) * 8;      // pre-swizzled k-element offset

    f32x4 acc[4][4];
#pragma unroll
    for (int i = 0; i < 4; ++i)
#pragma unroll
        for (int j = 0; j < 4; ++j) acc[i][j] = (f32x4){0.f, 0.f, 0.f, 0.f};

#define PROJ_STAGE(BUF, K0)                                                   \
    do {                                                                      \
        _Pragma("unroll")                                                     \
        for (int i = 0; i < 4; ++i) {                                         \
            int row = i * 32 + w * 8 + rsub;                                  \
            load_lds16(Wb + (size_t)(m0 + row) * C_ + (K0) + colp,            \
                       (char*)Ws_s[BUF] + i * 4096 + t * 16);                 \
        }                                                                     \
        _Pragma("unroll")                                                     \
        for (int i = 0; i < 4; ++i) {                                         \
            int row = i * 32 + w * 8 + rsub;                                  \
            int nn = n0 + row; if (nn >= N_) nn = N_ - 1;                     \
            load_lds16(Ab + (size_t)nn * C_ + (K0) + colp,                    \
                       (char*)As_s[BUF] + i * 4096 + t * 16);                 \
        }                                                                     \
    } while (0)

#define PROJ_COMPUTE(BUF)                                                     \
    do {                                                                      \
        _Pragma("unroll")                                                     \
        for (int ks = 0; ks < 2; ++ks) {                                      \
            short8 af[4], bfv[4];                                             \
            _Pragma("unroll")                                                 \
            for (int mi = 0; mi < 4; ++mi) {                                  \
                int row = wr * 64 + mi * 16 + r16;                            \
                int off = row * 128 + ((ks * 64 + kg * 16) ^ ((row & 7) << 4)); \
                af[mi] = *(const short8*)((const char*)Ws_s[BUF] + off);      \
            }                                                                 \
            _Pragma("unroll")                                                 \
            for (int nj = 0; nj < 4; ++nj) {                                  \
                int row = wc * 64 + nj * 16 + r16;                            \
                int off = row * 128 + ((ks * 64 + kg * 16) ^ ((row & 7) << 4)); \
                bfv[nj] = *(const short8*)((const char*)As_s[BUF] + off);     \
            }                                                                 \
            _Pragma("unroll")                                                 \
            for (int mi = 0; mi < 4; ++mi)                                    \
                _Pragma("unroll")                                             \
                for (int nj = 0; nj < 4; ++nj)                                \
                    acc[mi][nj] = __builtin_amdgcn_mfma_f32_16x16x32_bf16(    \
                        af[mi], bfv[nj], acc[mi][nj], 0, 0, 0);               \
        }                                                                     \
    } while (0)

    PROJ_STAGE(0, 0);
    __syncthreads();                      // drain prologue loads
    int cur = 0;
#pragma unroll
    for (int k = 0; k < 7; ++k) {
        PROJ_STAGE(cur ^ 1, (k + 1) * 64);   // next tile in flight...
        PROJ_COMPUTE(cur);                    // ...hidden under current MFMA
        __syncthreads();                      // vmcnt(0)+lgkm(0)+barrier
        cur ^= 1;
    }
    PROJ_COMPUTE(cur);

    float* ob = out + ((size_t)(b0 + b_l) * C_) * N_;
#pragma unroll
    for (int mi = 0; mi < 4; ++mi) {
        int cobase = m0 + wr * 64 + mi * 16 + kg * 4;
#pragma unroll
        for (int r = 0; r < 4; ++r) {
            int co = cobase + r;
            float bi = bias[co];
#pragma unroll
            for (int nj = 0; nj < 4; ++nj) {
                int n = n0 + wc * 64 + nj * 16 + r16;
                if (n < N_) ob[(size_t)co * N_ + n] = acc[mi][nj][r] + bi;
            }
        }
    }
#undef PROJ_STAGE
#undef PROJ_COMPUTE
}

extern "C" void kernel_launch(void* const* d_in, const int* in_sizes, int n_in,
                              void* d_out, int out_size, void* d_ws, size_t ws_size,
                              hipStream_t stream) {
    const float* x     = (const float*)d_in[0];
    const float* cw    = (const float*)d_in[1];
    const float* gamma = (const float*)d_in[2];
    const float* beta  = (const float*)d_in[3];
    const float* mean  = (const float*)d_in[4];
    const float* var   = (const float*)d_in[5];
    const float* pw    = (const float*)d_in[6];
    const float* pb    = (const float*)d_in[7];
    float* out = (float*)d_out;
    char* wsp = (char*)d_ws;

    const size_t W_B = (size_t)C_ * C_ * sizeof(bf16);              // 524,288

    // Single-pass (all 16 batches) if workspace allows; else two passes of 8.
    size_t qk16   = (size_t)16 * 2 * C_ * N_ * sizeof(bf16);        // 102.8 MB
    size_t v16    = (size_t)16 * C_ * N_ * sizeof(bf16);            //  51.4 MB
    size_t part16 = (size_t)SPLIT * 16 * NH * 4096 * 4;             //  14.7 MB
    size_t pt16   = (size_t)16 * NH * 4096 * 4;                     //   2.1 MB

    int nbs[2]; int ngroups;
    if (ws_size >= qk16 + v16 + part16 + pt16 + W_B) {
        ngroups = 1; nbs[0] = 16;
    } else {
        ngroups = 2; nbs[0] = 8; nbs[1] = 8;
    }

    int b0 = 0;
    for (int gi = 0; gi < ngroups; ++gi) {
        int nb = nbs[gi];
        size_t QK_B   = (size_t)nb * 2 * C_ * N_ * sizeof(bf16);
        size_t V_B    = (size_t)nb * C_ * N_ * sizeof(bf16);
        size_t PART_B = (size_t)SPLIT * nb * NH * 4096 * 4;
        size_t PT_B   = (size_t)nb * NH * 4096 * 4;
        bf16*  qk   = (bf16*)wsp;
        bf16*  v    = (bf16*)(wsp + QK_B);
        float* part = (float*)(wsp + QK_B + V_B);
        float* PT   = (float*)(wsp + QK_B + V_B + PART_B);
        bf16*  Wbf  = (bf16*)(wsp + QK_B + V_B + PART_B + PT_B);
        bf16*  outA = qk;                  // reuse q,k region after gram
        int bhTot = nb * NH;

        if (gi == 0)
            wconv_kernel<<<(C_ * C_) / 256, 256, 0, stream>>>(pw, Wbf);

        conv_bn_kernel<<<nb * (C_ / ICPB), 448, 0, stream>>>(
            x, cw, gamma, beta, mean, var, qk, v, b0);
        gram_mfma_kernel<<<bhTot * SPLIT, 256, 0, stream>>>(qk, part, bhTot);
        softmax_kernel<<<bhTot * 64, 64, 0, stream>>>(part, PT, bhTot);
        pv_kernel<<<bhTot * 7, 256, 0, stream>>>(v, PT, outA);
        proj_mfma_kernel<<<nb * 4 * 25, 256, 0, stream>>>(outA, Wbf, pb, out, b0, nb * 100);
        b0 += nb;
    }
}

// Round 12
// 207.733 us; speedup vs baseline: 1.1549x; 1.1549x over previous
//
#include <hip/hip_runtime.h>
#include <math.h>

#define B_ 16
#define C_ 512
#define H_ 56
#define W_ 56
#define N_ 3136          // H_*W_ = 49*64
#define NH 8
#define HD 64
#define SPLIT 7          // n-split for gram; 3136/7 = 448

typedef unsigned short bf16;
typedef __attribute__((ext_vector_type(8))) short short8;
typedef __attribute__((ext_vector_type(4))) float f32x4;

__device__ inline float bf2f(unsigned short u) {
    union { unsigned int i; float f; } v; v.i = ((unsigned int)u) << 16; return v.f;
}
__device__ inline unsigned short f2bf(float f) {
    union { float f; unsigned int i; } v; v.f = f;
    unsigned int r = v.i + 0x7fffu + ((v.i >> 16) & 1u);
    return (unsigned short)(r >> 16);
}

// async global->LDS, 16B per lane, linear dest (wave-uniform base + lane*16)
__device__ inline void load_lds16(const void* g, void* l) {
    __builtin_amdgcn_global_load_lds(
        (const __attribute__((address_space(1))) void*)g,
        (__attribute__((address_space(3))) void*)l, 16, 0, 0);
}

// ---------------------------------------------------------------------------
// Depthwise 3x3 conv + BN. Block = (b_l, ic); filter/BN consts block-uniform.
// 448 threads; thread t < 392 owns one 8-wide group; n0 = 8t (coalesced).
// (Round-10 version — ICPB=4 variant regressed, reverted.)
// ---------------------------------------------------------------------------
__global__ __launch_bounds__(448) void conv_bn_kernel(
    const float* __restrict__ x, const float* __restrict__ cw,
    const float* __restrict__ gamma, const float* __restrict__ beta,
    const float* __restrict__ mean, const float* __restrict__ var,
    bf16* __restrict__ qkdst, bf16* __restrict__ vdst, int b0)
{
    int bid = blockIdx.x;                 // nb*C_
    int ic = bid & 511; int b_l = bid >> 9;
    int b = b0 + b_l;
    const float* xin = x + ((size_t)b * C_ + ic) * N_;

    float w9[3][9], inv3[3], bias3[3];
#pragma unroll
    for (int t = 0; t < 3; ++t) {
        int o = ic * 3 + t;
#pragma unroll
        for (int k = 0; k < 9; ++k) w9[t][k] = cw[o * 9 + k];
        float iv = gamma[o] * rsqrtf(var[o] + 1e-5f);
        inv3[t] = iv;
        bias3[t] = fmaf(-mean[o], iv, beta[o]);
    }

    int t = threadIdx.x;
    if (t < 392) {
        int yy = t / 7;
        int xx0 = (t - yy * 7) * 8;
        int n0 = t * 8;                   // == yy*56 + xx0
        float vin[3][10];
#pragma unroll
        for (int dy = 0; dy < 3; ++dy) {
            int y2 = yy + dy - 1;
            bool rowok = (y2 >= 0) && (y2 < H_);
            const float* rp = xin + y2 * W_ + xx0;
            if (rowok) {
                float4 a = *(const float4*)rp;
                float4 c4 = *(const float4*)(rp + 4);
                vin[dy][1] = a.x;  vin[dy][2] = a.y;  vin[dy][3] = a.z;  vin[dy][4] = a.w;
                vin[dy][5] = c4.x; vin[dy][6] = c4.y; vin[dy][7] = c4.z; vin[dy][8] = c4.w;
                vin[dy][0] = (xx0 > 0)  ? rp[-1] : 0.f;
                vin[dy][9] = (xx0 < 48) ? rp[8]  : 0.f;
            } else {
#pragma unroll
                for (int j = 0; j < 10; ++j) vin[dy][j] = 0.f;
            }
        }
#pragma unroll
        for (int ft = 0; ft < 3; ++ft) {
            int o = ic * 3 + ft;          // uniform
            int s = o >> 9;               // uniform
            int c = o & 511;
            short8 r8;
#pragma unroll
            for (int j = 0; j < 8; ++j) {
                float acc = 0.f;
#pragma unroll
                for (int ky = 0; ky < 3; ++ky)
#pragma unroll
                    for (int kx = 0; kx < 3; ++kx)
                        acc = fmaf(vin[ky][j + kx], w9[ft][ky*3+kx], acc);
                r8[j] = (short)f2bf(fmaf(acc, inv3[ft], bias3[ft]));
            }
            bf16* dst = (s < 2)
                ? qkdst + (((size_t)b_l * 2 + s) * C_ + c) * N_
                : vdst + ((size_t)b_l * C_ + c) * N_;
            *(short8*)(dst + n0) = r8;
        }
    }
}

// ---------------------------------------------------------------------------
// Gram partials via MFMA (T2 swizzle + gload_lds):
//   part[s][bh][d*64+e] = sum_{n in split s} q[d,n]*k[e,n]
// ---------------------------------------------------------------------------
__global__ __launch_bounds__(256) void gram_mfma_kernel(
    const bf16* __restrict__ qk, float* __restrict__ part, int bhTot)
{
    __shared__ bf16 qs[64 * 64];
    __shared__ bf16 ks[64 * 64];
    int bid = blockIdx.x;                 // bhTot*SPLIT
    int s = bid % SPLIT; int bh = bid / SPLIT;
    int h = bh % NH; int b_l = bh / NH;
    const bf16* qp = qk + (((size_t)b_l * 2 + 0) * C_ + h * HD) * N_;
    const bf16* kp = qk + (((size_t)b_l * 2 + 1) * C_ + h * HD) * N_;
    int t = threadIdx.x;
    int w = t >> 6, l = t & 63;
    int r16 = l & 15, kg = l >> 4;
    int wr = w >> 1, wc = w & 1;
    int rsub = l >> 3;
    int colp = ((l & 7) ^ rsub) * 8;      // pre-swizzled n-element offset
    int n0 = s * (N_ / SPLIT);

    f32x4 acc[2][2];
#pragma unroll
    for (int i = 0; i < 2; ++i)
#pragma unroll
        for (int j = 0; j < 2; ++j) acc[i][j] = (f32x4){0.f, 0.f, 0.f, 0.f};

    for (int nc = 0; nc < N_ / SPLIT; nc += 64) {
        int nb = n0 + nc;
#pragma unroll
        for (int i = 0; i < 2; ++i) {
            int row = i * 32 + w * 8 + rsub;
            load_lds16(qp + (size_t)row * N_ + nb + colp, (char*)qs + i * 4096 + t * 16);
            load_lds16(kp + (size_t)row * N_ + nb + colp, (char*)ks + i * 4096 + t * 16);
        }
        __syncthreads();
#pragma unroll
        for (int ksb = 0; ksb < 2; ++ksb) {
            short8 af[2], bfv[2];
#pragma unroll
            for (int mi = 0; mi < 2; ++mi) {
                int row = wr * 32 + mi * 16 + r16;
                int off = row * 128 + ((ksb * 64 + kg * 16) ^ ((row & 7) << 4));
                af[mi] = *(const short8*)((const char*)qs + off);
            }
#pragma unroll
            for (int nj = 0; nj < 2; ++nj) {
                int row = wc * 32 + nj * 16 + r16;
                int off = row * 128 + ((ksb * 64 + kg * 16) ^ ((row & 7) << 4));
                bfv[nj] = *(const short8*)((const char*)ks + off);
            }
#pragma unroll
            for (int mi = 0; mi < 2; ++mi)
#pragma unroll
                for (int nj = 0; nj < 2; ++nj)
                    acc[mi][nj] = __builtin_amdgcn_mfma_f32_16x16x32_bf16(
                        af[mi], bfv[nj], acc[mi][nj], 0, 0, 0);
        }
        __syncthreads();
    }
    float* pp = part + ((size_t)s * bhTot + bh) * 4096;
#pragma unroll
    for (int mi = 0; mi < 2; ++mi)
#pragma unroll
        for (int nj = 0; nj < 2; ++nj) {
            int e = wc * 32 + nj * 16 + r16;
#pragma unroll
            for (int r = 0; r < 4; ++r) {
                int d = wr * 32 + mi * 16 + kg * 4 + r;
                pp[d * 64 + e] = acc[mi][nj][r];
            }
        }
}

// ---------------------------------------------------------------------------
// Reduce partials, scale, softmax over e. One wave per (bh,d) row.
// Writes P TRANSPOSED: PT[bh][e*64+d].
// ---------------------------------------------------------------------------
__global__ __launch_bounds__(64) void softmax_kernel(
    const float* __restrict__ part, float* __restrict__ PT, int bhTot)
{
    int row = blockIdx.x;                 // bh*64 + d
    int e = threadIdx.x;
    size_t base = (size_t)row * 64 + e;
    float val = 0.f;
#pragma unroll
    for (int s = 0; s < SPLIT; ++s) val += part[(size_t)s * bhTot * 4096 + base];
    val *= 0.125f;                        // hd^-0.5
    float m = val;
#pragma unroll
    for (int off = 32; off > 0; off >>= 1) m = fmaxf(m, __shfl_xor(m, off));
    float ex = expf(val - m);
    float sum = ex;
#pragma unroll
    for (int off = 32; off > 0; off >>= 1) sum += __shfl_xor(sum, off);
    PT[(size_t)(row >> 6) * 4096 + (size_t)e * 64 + (row & 63)] = ex / sum;
}

// ---------------------------------------------------------------------------
// outA[b_l][d][h][n] = sum_e PT[e][d] * v[b_l][h*64+e][n]   (bf16 out)
// (Round-10 version — 49 tiles/bh, one tile per block.)
// ---------------------------------------------------------------------------
__global__ __launch_bounds__(256) void pv_kernel(
    const bf16* __restrict__ v, const float* __restrict__ PT,
    bf16* __restrict__ outA)
{
    __shared__ float pts[4096];           // PT[e][d] 16KB
    __shared__ bf16 vs[64 * 64];          // vs[e][n] 8KB
    int bid = blockIdx.x;                 // bhTot*49
    int nt = bid % 49; int bh = bid / 49;
    int h = bh % NH, b_l = bh / NH;
    int t = threadIdx.x;
    const float* ptg = PT + (size_t)bh * 4096;
#pragma unroll
    for (int i = 0; i < 4; ++i)
        load_lds16(ptg + i * 1024 + t * 4, (char*)pts + i * 4096 + t * 16);
    const bf16* vb = v + ((size_t)b_l * C_ + h * HD) * N_ + nt * 64;
#pragma unroll
    for (int i = 0; i < 2; ++i) {
        int row = i * 32 + (t >> 3);
        load_lds16(vb + (size_t)row * N_ + (t & 7) * 8, (char*)vs + i * 4096 + t * 16);
    }
    __syncthreads();

    int ng = t & 15, dg = t >> 4;         // n0 = ng*4, d0 = dg*4
    float acc[4][4] = {};
#pragma unroll 16
    for (int e = 0; e < 64; ++e) {
        float4 p = *(const float4*)&pts[e * 64 + dg * 4];
        ushort4 vv = *(const ushort4*)&vs[e * 64 + ng * 4];
        float v0 = bf2f(vv.x), v1 = bf2f(vv.y), v2 = bf2f(vv.z), v3 = bf2f(vv.w);
        float p4[4] = {p.x, p.y, p.z, p.w};
#pragma unroll
        for (int i = 0; i < 4; ++i) {
            acc[i][0] = fmaf(p4[i], v0, acc[i][0]);
            acc[i][1] = fmaf(p4[i], v1, acc[i][1]);
            acc[i][2] = fmaf(p4[i], v2, acc[i][2]);
            acc[i][3] = fmaf(p4[i], v3, acc[i][3]);
        }
    }
    bf16* op = outA + (size_t)b_l * (C_*N_) + (size_t)h * N_ + nt * 64 + ng * 4;
#pragma unroll
    for (int i = 0; i < 4; ++i) {
        ushort4 r4;
        unsigned short* rr = (unsigned short*)&r4;
        rr[0] = f2bf(acc[i][0]); rr[1] = f2bf(acc[i][1]);
        rr[2] = f2bf(acc[i][2]); rr[3] = f2bf(acc[i][3]);
        *(ushort4*)(op + (size_t)(dg * 4 + i) * (NH*N_)) = r4;
    }
}

// ---------------------------------------------------------------------------
// Convert projection weights f32 -> bf16 (512x512).
// ---------------------------------------------------------------------------
__global__ __launch_bounds__(256) void wconv_kernel(
    const float* __restrict__ w, bf16* __restrict__ wb)
{
    int i = blockIdx.x * 256 + threadIdx.x;   // 262144 total
    wb[i] = f2bf(w[i]);
}

// ---------------------------------------------------------------------------
// MFMA projection, SINGLE 32KB buffer (4-5 blocks/CU; wave-level overlap does
// the latency hiding — 64KB dbuf halved occupancy for net 0) + XCD-chunked
// swizzle with mt fastest (A-quad on one XCD; FETCH 108->33MB, keep).
//   out[b0+b_l][co][n] = sum_c Wb[co][c]*A[b_l][n][c] + pb[co]
// ---------------------------------------------------------------------------
__global__ __launch_bounds__(256) void proj_mfma_kernel(
    const bf16* __restrict__ A, const bf16* __restrict__ Wb,
    const float* __restrict__ bias, float* __restrict__ out, int b0, int nwg)
{
    __shared__ bf16 Ws_s[128 * 64];
    __shared__ bf16 As_s[128 * 64];
    int bid = blockIdx.x;                 // nwg = nb*100, nwg % 8 == 0
    int cpx = nwg >> 3;                   // chunk per XCD (200: % 4 == 0)
    int swz = (bid & 7) * cpx + (bid >> 3);
    int b_l = swz / 100; int rem = swz % 100;
    int nt = rem >> 2, mt = rem & 3;      // mt fastest: A-quad on one XCD
    int m0 = mt * 128, n0 = nt * 128;
    int t = threadIdx.x;
    int w = t >> 6, l = t & 63;
    int r16 = l & 15, kg = l >> 4;        // frag row / k-group
    int wr = w >> 1, wc = w & 1;          // wave quadrant
    const bf16* Ab = A + (size_t)b_l * N_ * C_;
    int rsub = l >> 3;                    // row within the 8-row wave chunk
    int colp = ((l & 7) ^ rsub) * 8;      // pre-swizzled k-element offset

    f32x4 acc[4][4];
#pragma unroll
    for (int i = 0; i < 4; ++i)
#pragma unroll
        for (int j = 0; j < 4; ++j) acc[i][j] = (f32x4){0.f, 0.f, 0.f, 0.f};

    for (int k0 = 0; k0 < C_; k0 += 64) {
#pragma unroll
        for (int i = 0; i < 4; ++i) {
            int row = i * 32 + w * 8 + rsub;
            load_lds16(Wb + (size_t)(m0 + row) * C_ + k0 + colp,
                       (char*)Ws_s + i * 4096 + t * 16);
        }
#pragma unroll
        for (int i = 0; i < 4; ++i) {
            int row = i * 32 + w * 8 + rsub;
            int nn = n0 + row; if (nn >= N_) nn = N_ - 1;
            load_lds16(Ab + (size_t)nn * C_ + k0 + colp,
                       (char*)As_s + i * 4096 + t * 16);
        }
        __syncthreads();
#pragma unroll
        for (int ks = 0; ks < 2; ++ks) {
            short8 af[4], bfv[4];
#pragma unroll
            for (int mi = 0; mi < 4; ++mi) {
                int row = wr * 64 + mi * 16 + r16;
                int off = row * 128 + ((ks * 64 + kg * 16) ^ ((row & 7) << 4));
                af[mi] = *(const short8*)((const char*)Ws_s + off);
            }
#pragma unroll
            for (int nj = 0; nj < 4; ++nj) {
                int row = wc * 64 + nj * 16 + r16;
                int off = row * 128 + ((ks * 64 + kg * 16) ^ ((row & 7) << 4));
                bfv[nj] = *(const short8*)((const char*)As_s + off);
            }
#pragma unroll
            for (int mi = 0; mi < 4; ++mi)
#pragma unroll
                for (int nj = 0; nj < 4; ++nj)
                    acc[mi][nj] = __builtin_amdgcn_mfma_f32_16x16x32_bf16(
                        af[mi], bfv[nj], acc[mi][nj], 0, 0, 0);
        }
        __syncthreads();
    }
    float* ob = out + ((size_t)(b0 + b_l) * C_) * N_;
#pragma unroll
    for (int mi = 0; mi < 4; ++mi) {
        int cobase = m0 + wr * 64 + mi * 16 + kg * 4;
#pragma unroll
        for (int r = 0; r < 4; ++r) {
            int co = cobase + r;
            float bi = bias[co];
#pragma unroll
            for (int nj = 0; nj < 4; ++nj) {
                int n = n0 + wc * 64 + nj * 16 + r16;
                if (n < N_) ob[(size_t)co * N_ + n] = acc[mi][nj][r] + bi;
            }
        }
    }
}

extern "C" void kernel_launch(void* const* d_in, const int* in_sizes, int n_in,
                              void* d_out, int out_size, void* d_ws, size_t ws_size,
                              hipStream_t stream) {
    const float* x     = (const float*)d_in[0];
    const float* cw    = (const float*)d_in[1];
    const float* gamma = (const float*)d_in[2];
    const float* beta  = (const float*)d_in[3];
    const float* mean  = (const float*)d_in[4];
    const float* var   = (const float*)d_in[5];
    const float* pw    = (const float*)d_in[6];
    const float* pb    = (const float*)d_in[7];
    float* out = (float*)d_out;
    char* wsp = (char*)d_ws;

    const size_t W_B = (size_t)C_ * C_ * sizeof(bf16);              // 524,288

    // Single-pass (all 16 batches) if workspace allows; else two passes of 8.
    size_t qk16   = (size_t)16 * 2 * C_ * N_ * sizeof(bf16);        // 102.8 MB
    size_t v16    = (size_t)16 * C_ * N_ * sizeof(bf16);            //  51.4 MB
    size_t part16 = (size_t)SPLIT * 16 * NH * 4096 * 4;             //  14.7 MB
    size_t pt16   = (size_t)16 * NH * 4096 * 4;                     //   2.1 MB

    int nbs[2]; int ngroups;
    if (ws_size >= qk16 + v16 + part16 + pt16 + W_B) {
        ngroups = 1; nbs[0] = 16;
    } else {
        ngroups = 2; nbs[0] = 8; nbs[1] = 8;
    }

    int b0 = 0;
    for (int gi = 0; gi < ngroups; ++gi) {
        int nb = nbs[gi];
        size_t QK_B   = (size_t)nb * 2 * C_ * N_ * sizeof(bf16);
        size_t V_B    = (size_t)nb * C_ * N_ * sizeof(bf16);
        size_t PART_B = (size_t)SPLIT * nb * NH * 4096 * 4;
        size_t PT_B   = (size_t)nb * NH * 4096 * 4;
        bf16*  qk   = (bf16*)wsp;
        bf16*  v    = (bf16*)(wsp + QK_B);
        float* part = (float*)(wsp + QK_B + V_B);
        float* PT   = (float*)(wsp + QK_B + V_B + PART_B);
        bf16*  Wbf  = (bf16*)(wsp + QK_B + V_B + PART_B + PT_B);
        bf16*  outA = qk;                  // reuse q,k region after gram
        int bhTot = nb * NH;

        if (gi == 0)
            wconv_kernel<<<(C_ * C_) / 256, 256, 0, stream>>>(pw, Wbf);

        conv_bn_kernel<<<nb * C_, 448, 0, stream>>>(
            x, cw, gamma, beta, mean, var, qk, v, b0);
        gram_mfma_kernel<<<bhTot * SPLIT, 256, 0, stream>>>(qk, part, bhTot);
        softmax_kernel<<<bhTot * 64, 64, 0, stream>>>(part, PT, bhTot);
        pv_kernel<<<bhTot * 49, 256, 0, stream>>>(v, PT, outA);
        proj_mfma_kernel<<<nb * 4 * 25, 256, 0, stream>>>(outA, Wbf, pb, out, b0, nb * 100);
        b0 += nb;
    }
}

// Round 13
// 205.764 us; speedup vs baseline: 1.1659x; 1.0096x over previous
//
#include <hip/hip_runtime.h>
#include <hip/hip_bf16.h>
#include <math.h>

#define B_ 16
#define C_ 512
#define H_ 56
#define W_ 56
#define N_ 3136          // H_*W_ = 49*64
#define NH 8
#define HD 64
#define SPLIT 7          // n-split for gram; 3136/7 = 448

typedef unsigned short bf16;
typedef __attribute__((ext_vector_type(8))) short short8;
typedef __attribute__((ext_vector_type(4))) float f32x4;

__device__ inline float bf2f(unsigned short u) {
    union { unsigned int i; float f; } v; v.i = ((unsigned int)u) << 16; return v.f;
}
// Compiler-native conversion (RNE): pairs get packed into v_cvt_pk_bf16_f32.
__device__ inline unsigned short f2bf(float f) {
    union { __hip_bfloat16 h; unsigned short u; } v;
    v.h = __float2bfloat16(f);
    return v.u;
}

// async global->LDS, 16B per lane, linear dest (wave-uniform base + lane*16)
__device__ inline void load_lds16(const void* g, void* l) {
    __builtin_amdgcn_global_load_lds(
        (const __attribute__((address_space(1))) void*)g,
        (__attribute__((address_space(3))) void*)l, 16, 0, 0);
}

// ---------------------------------------------------------------------------
// Depthwise 3x3 conv + BN. Block = (b_l, ic); filter/BN consts block-uniform.
// 448 threads; thread t < 392 owns one 8-wide group; n0 = 8t (coalesced).
// ---------------------------------------------------------------------------
__global__ __launch_bounds__(448) void conv_bn_kernel(
    const float* __restrict__ x, const float* __restrict__ cw,
    const float* __restrict__ gamma, const float* __restrict__ beta,
    const float* __restrict__ mean, const float* __restrict__ var,
    bf16* __restrict__ qkdst, bf16* __restrict__ vdst, int b0)
{
    int bid = blockIdx.x;                 // nb*C_
    int ic = bid & 511; int b_l = bid >> 9;
    int b = b0 + b_l;
    const float* xin = x + ((size_t)b * C_ + ic) * N_;

    float w9[3][9], inv3[3], bias3[3];
#pragma unroll
    for (int t = 0; t < 3; ++t) {
        int o = ic * 3 + t;
#pragma unroll
        for (int k = 0; k < 9; ++k) w9[t][k] = cw[o * 9 + k];
        float iv = gamma[o] * rsqrtf(var[o] + 1e-5f);
        inv3[t] = iv;
        bias3[t] = fmaf(-mean[o], iv, beta[o]);
    }

    int t = threadIdx.x;
    if (t < 392) {
        int yy = t / 7;
        int xx0 = (t - yy * 7) * 8;
        int n0 = t * 8;                   // == yy*56 + xx0
        float vin[3][10];
#pragma unroll
        for (int dy = 0; dy < 3; ++dy) {
            int y2 = yy + dy - 1;
            bool rowok = (y2 >= 0) && (y2 < H_);
            const float* rp = xin + y2 * W_ + xx0;
            if (rowok) {
                float4 a = *(const float4*)rp;
                float4 c4 = *(const float4*)(rp + 4);
                vin[dy][1] = a.x;  vin[dy][2] = a.y;  vin[dy][3] = a.z;  vin[dy][4] = a.w;
                vin[dy][5] = c4.x; vin[dy][6] = c4.y; vin[dy][7] = c4.z; vin[dy][8] = c4.w;
                vin[dy][0] = (xx0 > 0)  ? rp[-1] : 0.f;
                vin[dy][9] = (xx0 < 48) ? rp[8]  : 0.f;
            } else {
#pragma unroll
                for (int j = 0; j < 10; ++j) vin[dy][j] = 0.f;
            }
        }
#pragma unroll
        for (int ft = 0; ft < 3; ++ft) {
            int o = ic * 3 + ft;          // uniform
            int s = o >> 9;               // uniform
            int c = o & 511;
            float r[8];
#pragma unroll
            for (int j = 0; j < 8; ++j) {
                float acc = 0.f;
#pragma unroll
                for (int ky = 0; ky < 3; ++ky)
#pragma unroll
                    for (int kx = 0; kx < 3; ++kx)
                        acc = fmaf(vin[ky][j + kx], w9[ft][ky*3+kx], acc);
                r[j] = fmaf(acc, inv3[ft], bias3[ft]);
            }
            short8 r8;
#pragma unroll
            for (int j = 0; j < 8; ++j) r8[j] = (short)f2bf(r[j]);
            bf16* dst = (s < 2)
                ? qkdst + (((size_t)b_l * 2 + s) * C_ + c) * N_
                : vdst + ((size_t)b_l * C_ + c) * N_;
            *(short8*)(dst + n0) = r8;
        }
    }
}

// ---------------------------------------------------------------------------
// Gram partials via MFMA (T2 swizzle + gload_lds):
//   part[s][bh][d*64+e] = sum_{n in split s} q[d,n]*k[e,n]
// ---------------------------------------------------------------------------
__global__ __launch_bounds__(256) void gram_mfma_kernel(
    const bf16* __restrict__ qk, float* __restrict__ part, int bhTot)
{
    __shared__ bf16 qs[64 * 64];
    __shared__ bf16 ks[64 * 64];
    int bid = blockIdx.x;                 // bhTot*SPLIT
    int s = bid % SPLIT; int bh = bid / SPLIT;
    int h = bh % NH; int b_l = bh / NH;
    const bf16* qp = qk + (((size_t)b_l * 2 + 0) * C_ + h * HD) * N_;
    const bf16* kp = qk + (((size_t)b_l * 2 + 1) * C_ + h * HD) * N_;
    int t = threadIdx.x;
    int w = t >> 6, l = t & 63;
    int r16 = l & 15, kg = l >> 4;
    int wr = w >> 1, wc = w & 1;
    int rsub = l >> 3;
    int colp = ((l & 7) ^ rsub) * 8;      // pre-swizzled n-element offset
    int n0 = s * (N_ / SPLIT);

    f32x4 acc[2][2];
#pragma unroll
    for (int i = 0; i < 2; ++i)
#pragma unroll
        for (int j = 0; j < 2; ++j) acc[i][j] = (f32x4){0.f, 0.f, 0.f, 0.f};

    for (int nc = 0; nc < N_ / SPLIT; nc += 64) {
        int nb = n0 + nc;
#pragma unroll
        for (int i = 0; i < 2; ++i) {
            int row = i * 32 + w * 8 + rsub;
            load_lds16(qp + (size_t)row * N_ + nb + colp, (char*)qs + i * 4096 + t * 16);
            load_lds16(kp + (size_t)row * N_ + nb + colp, (char*)ks + i * 4096 + t * 16);
        }
        __syncthreads();
#pragma unroll
        for (int ksb = 0; ksb < 2; ++ksb) {
            short8 af[2], bfv[2];
#pragma unroll
            for (int mi = 0; mi < 2; ++mi) {
                int row = wr * 32 + mi * 16 + r16;
                int off = row * 128 + ((ksb * 64 + kg * 16) ^ ((row & 7) << 4));
                af[mi] = *(const short8*)((const char*)qs + off);
            }
#pragma unroll
            for (int nj = 0; nj < 2; ++nj) {
                int row = wc * 32 + nj * 16 + r16;
                int off = row * 128 + ((ksb * 64 + kg * 16) ^ ((row & 7) << 4));
                bfv[nj] = *(const short8*)((const char*)ks + off);
            }
#pragma unroll
            for (int mi = 0; mi < 2; ++mi)
#pragma unroll
                for (int nj = 0; nj < 2; ++nj)
                    acc[mi][nj] = __builtin_amdgcn_mfma_f32_16x16x32_bf16(
                        af[mi], bfv[nj], acc[mi][nj], 0, 0, 0);
        }
        __syncthreads();
    }
    float* pp = part + ((size_t)s * bhTot + bh) * 4096;
#pragma unroll
    for (int mi = 0; mi < 2; ++mi)
#pragma unroll
        for (int nj = 0; nj < 2; ++nj) {
            int e = wc * 32 + nj * 16 + r16;
#pragma unroll
            for (int r = 0; r < 4; ++r) {
                int d = wr * 32 + mi * 16 + kg * 4 + r;
                pp[d * 64 + e] = acc[mi][nj][r];
            }
        }
}

// ---------------------------------------------------------------------------
// Reduce partials, scale, softmax over e. One wave per (bh,d) row.
// Writes P TRANSPOSED: PT[bh][e*64+d].
// ---------------------------------------------------------------------------
__global__ __launch_bounds__(64) void softmax_kernel(
    const float* __restrict__ part, float* __restrict__ PT, int bhTot)
{
    int row = blockIdx.x;                 // bh*64 + d
    int e = threadIdx.x;
    size_t base = (size_t)row * 64 + e;
    float val = 0.f;
#pragma unroll
    for (int s = 0; s < SPLIT; ++s) val += part[(size_t)s * bhTot * 4096 + base];
    val *= 0.125f;                        // hd^-0.5
    float m = val;
#pragma unroll
    for (int off = 32; off > 0; off >>= 1) m = fmaxf(m, __shfl_xor(m, off));
    float ex = expf(val - m);
    float sum = ex;
#pragma unroll
    for (int off = 32; off > 0; off >>= 1) sum += __shfl_xor(sum, off);
    PT[(size_t)(row >> 6) * 4096 + (size_t)e * 64 + (row & 63)] = ex / sum;
}

// ---------------------------------------------------------------------------
// outA[b_l][d][h][n] = sum_e PT[e][d] * v[b_l][h*64+e][n]   (bf16 out)
// ---------------------------------------------------------------------------
__global__ __launch_bounds__(256) void pv_kernel(
    const bf16* __restrict__ v, const float* __restrict__ PT,
    bf16* __restrict__ outA)
{
    __shared__ float pts[4096];           // PT[e][d] 16KB
    __shared__ bf16 vs[64 * 64];          // vs[e][n] 8KB
    int bid = blockIdx.x;                 // bhTot*49
    int nt = bid % 49; int bh = bid / 49;
    int h = bh % NH, b_l = bh / NH;
    int t = threadIdx.x;
    const float* ptg = PT + (size_t)bh * 4096;
#pragma unroll
    for (int i = 0; i < 4; ++i)
        load_lds16(ptg + i * 1024 + t * 4, (char*)pts + i * 4096 + t * 16);
    const bf16* vb = v + ((size_t)b_l * C_ + h * HD) * N_ + nt * 64;
#pragma unroll
    for (int i = 0; i < 2; ++i) {
        int row = i * 32 + (t >> 3);
        load_lds16(vb + (size_t)row * N_ + (t & 7) * 8, (char*)vs + i * 4096 + t * 16);
    }
    __syncthreads();

    int ng = t & 15, dg = t >> 4;         // n0 = ng*4, d0 = dg*4
    float acc[4][4] = {};
#pragma unroll 16
    for (int e = 0; e < 64; ++e) {
        float4 p = *(const float4*)&pts[e * 64 + dg * 4];
        ushort4 vv = *(const ushort4*)&vs[e * 64 + ng * 4];
        float v0 = bf2f(vv.x), v1 = bf2f(vv.y), v2 = bf2f(vv.z), v3 = bf2f(vv.w);
        float p4[4] = {p.x, p.y, p.z, p.w};
#pragma unroll
        for (int i = 0; i < 4; ++i) {
            acc[i][0] = fmaf(p4[i], v0, acc[i][0]);
            acc[i][1] = fmaf(p4[i], v1, acc[i][1]);
            acc[i][2] = fmaf(p4[i], v2, acc[i][2]);
            acc[i][3] = fmaf(p4[i], v3, acc[i][3]);
        }
    }
    bf16* op = outA + (size_t)b_l * (C_*N_) + (size_t)h * N_ + nt * 64 + ng * 4;
#pragma unroll
    for (int i = 0; i < 4; ++i) {
        ushort4 r4;
        unsigned short* rr = (unsigned short*)&r4;
        rr[0] = f2bf(acc[i][0]); rr[1] = f2bf(acc[i][1]);
        rr[2] = f2bf(acc[i][2]); rr[3] = f2bf(acc[i][3]);
        *(ushort4*)(op + (size_t)(dg * 4 + i) * (NH*N_)) = r4;
    }
}

// ---------------------------------------------------------------------------
// Convert projection weights f32 -> bf16 (512x512).
// ---------------------------------------------------------------------------
__global__ __launch_bounds__(256) void wconv_kernel(
    const float* __restrict__ w, bf16* __restrict__ wb)
{
    int i = blockIdx.x * 256 + threadIdx.x;   // 262144 total
    wb[i] = f2bf(w[i]);
}

// ---------------------------------------------------------------------------
// MFMA projection, single 32KB buffer + XCD-chunked swizzle (mt fastest).
//   out[b0+b_l][co][n] = sum_c Wb[co][c]*A[b_l][n][c] + pb[co]
// Final stores non-temporal: `out` is never re-read; keep L2/L3 for inputs.
// ---------------------------------------------------------------------------
__global__ __launch_bounds__(256) void proj_mfma_kernel(
    const bf16* __restrict__ A, const bf16* __restrict__ Wb,
    const float* __restrict__ bias, float* __restrict__ out, int b0, int nwg)
{
    __shared__ bf16 Ws_s[128 * 64];
    __shared__ bf16 As_s[128 * 64];
    int bid = blockIdx.x;                 // nwg = nb*100, nwg % 8 == 0
    int cpx = nwg >> 3;                   // chunk per XCD (200: % 4 == 0)
    int swz = (bid & 7) * cpx + (bid >> 3);
    int b_l = swz / 100; int rem = swz % 100;
    int nt = rem >> 2, mt = rem & 3;      // mt fastest: A-quad on one XCD
    int m0 = mt * 128, n0 = nt * 128;
    int t = threadIdx.x;
    int w = t >> 6, l = t & 63;
    int r16 = l & 15, kg = l >> 4;        // frag row / k-group
    int wr = w >> 1, wc = w & 1;          // wave quadrant
    const bf16* Ab = A + (size_t)b_l * N_ * C_;
    int rsub = l >> 3;                    // row within the 8-row wave chunk
    int colp = ((l & 7) ^ rsub) * 8;      // pre-swizzled k-element offset

    f32x4 acc[4][4];
#pragma unroll
    for (int i = 0; i < 4; ++i)
#pragma unroll
        for (int j = 0; j < 4; ++j) acc[i][j] = (f32x4){0.f, 0.f, 0.f, 0.f};

    for (int k0 = 0; k0 < C_; k0 += 64) {
#pragma unroll
        for (int i = 0; i < 4; ++i) {
            int row = i * 32 + w * 8 + rsub;
            load_lds16(Wb + (size_t)(m0 + row) * C_ + k0 + colp,
                       (char*)Ws_s + i * 4096 + t * 16);
        }
#pragma unroll
        for (int i = 0; i < 4; ++i) {
            int row = i * 32 + w * 8 + rsub;
            int nn = n0 + row; if (nn >= N_) nn = N_ - 1;
            load_lds16(Ab + (size_t)nn * C_ + k0 + colp,
                       (char*)As_s + i * 4096 + t * 16);
        }
        __syncthreads();
#pragma unroll
        for (int ks = 0; ks < 2; ++ks) {
            short8 af[4], bfv[4];
#pragma unroll
            for (int mi = 0; mi < 4; ++mi) {
                int row = wr * 64 + mi * 16 + r16;
                int off = row * 128 + ((ks * 64 + kg * 16) ^ ((row & 7) << 4));
                af[mi] = *(const short8*)((const char*)Ws_s + off);
            }
#pragma unroll
            for (int nj = 0; nj < 4; ++nj) {
                int row = wc * 64 + nj * 16 + r16;
                int off = row * 128 + ((ks * 64 + kg * 16) ^ ((row & 7) << 4));
                bfv[nj] = *(const short8*)((const char*)As_s + off);
            }
#pragma unroll
            for (int mi = 0; mi < 4; ++mi)
#pragma unroll
                for (int nj = 0; nj < 4; ++nj)
                    acc[mi][nj] = __builtin_amdgcn_mfma_f32_16x16x32_bf16(
                        af[mi], bfv[nj], acc[mi][nj], 0, 0, 0);
        }
        __syncthreads();
    }
    float* ob = out + ((size_t)(b0 + b_l) * C_) * N_;
#pragma unroll
    for (int mi = 0; mi < 4; ++mi) {
        int cobase = m0 + wr * 64 + mi * 16 + kg * 4;
#pragma unroll
        for (int r = 0; r < 4; ++r) {
            int co = cobase + r;
            float bi = bias[co];
#pragma unroll
            for (int nj = 0; nj < 4; ++nj) {
                int n = n0 + wc * 64 + nj * 16 + r16;
                if (n < N_)
                    __builtin_nontemporal_store(acc[mi][nj][r] + bi,
                                                &ob[(size_t)co * N_ + n]);
            }
        }
    }
}

extern "C" void kernel_launch(void* const* d_in, const int* in_sizes, int n_in,
                              void* d_out, int out_size, void* d_ws, size_t ws_size,
                              hipStream_t stream) {
    const float* x     = (const float*)d_in[0];
    const float* cw    = (const float*)d_in[1];
    const float* gamma = (const float*)d_in[2];
    const float* beta  = (const float*)d_in[3];
    const float* mean  = (const float*)d_in[4];
    const float* var   = (const float*)d_in[5];
    const float* pw    = (const float*)d_in[6];
    const float* pb    = (const float*)d_in[7];
    float* out = (float*)d_out;
    char* wsp = (char*)d_ws;

    const size_t W_B = (size_t)C_ * C_ * sizeof(bf16);              // 524,288

    // Single-pass (all 16 batches) if workspace allows; else two passes of 8.
    size_t qk16   = (size_t)16 * 2 * C_ * N_ * sizeof(bf16);        // 102.8 MB
    size_t v16    = (size_t)16 * C_ * N_ * sizeof(bf16);            //  51.4 MB
    size_t part16 = (size_t)SPLIT * 16 * NH * 4096 * 4;             //  14.7 MB
    size_t pt16   = (size_t)16 * NH * 4096 * 4;                     //   2.1 MB

    int nbs[2]; int ngroups;
    if (ws_size >= qk16 + v16 + part16 + pt16 + W_B) {
        ngroups = 1; nbs[0] = 16;
    } else {
        ngroups = 2; nbs[0] = 8; nbs[1] = 8;
    }

    int b0 = 0;
    for (int gi = 0; gi < ngroups; ++gi) {
        int nb = nbs[gi];
        size_t QK_B   = (size_t)nb * 2 * C_ * N_ * sizeof(bf16);
        size_t V_B    = (size_t)nb * C_ * N_ * sizeof(bf16);
        size_t PART_B = (size_t)SPLIT * nb * NH * 4096 * 4;
        size_t PT_B   = (size_t)nb * NH * 4096 * 4;
        bf16*  qk   = (bf16*)wsp;
        bf16*  v    = (bf16*)(wsp + QK_B);
        float* part = (float*)(wsp + QK_B + V_B);
        float* PT   = (float*)(wsp + QK_B + V_B + PART_B);
        bf16*  Wbf  = (bf16*)(wsp + QK_B + V_B + PART_B + PT_B);
        bf16*  outA = qk;                  // reuse q,k region after gram
        int bhTot = nb * NH;

        if (gi == 0)
            wconv_kernel<<<(C_ * C_) / 256, 256, 0, stream>>>(pw, Wbf);

        conv_bn_kernel<<<nb * C_, 448, 0, stream>>>(
            x, cw, gamma, beta, mean, var, qk, v, b0);
        gram_mfma_kernel<<<bhTot * SPLIT, 256, 0, stream>>>(qk, part, bhTot);
        softmax_kernel<<<bhTot * 64, 64, 0, stream>>>(part, PT, bhTot);
        pv_kernel<<<bhTot * 49, 256, 0, stream>>>(v, PT, outA);
        proj_mfma_kernel<<<nb * 4 * 25, 256, 0, stream>>>(outA, Wbf, pb, out, b0, nb * 100);
        b0 += nb;
    }
}

// Round 14
// 196.135 us; speedup vs baseline: 1.2232x; 1.0491x over previous
//
#include <hip/hip_runtime.h>
#include <hip/hip_bf16.h>
#include <math.h>

#define B_ 16
#define C_ 512
#define H_ 56
#define W_ 56
#define N_ 3136          // H_*W_ = 49*64
#define NH 8
#define HD 64
#define SPLIT 7          // n-split for gram; 3136/7 = 448

typedef unsigned short bf16;
typedef __attribute__((ext_vector_type(8))) short short8;
typedef __attribute__((ext_vector_type(4))) float f32x4;

__device__ inline float bf2f(unsigned short u) {
    union { unsigned int i; float f; } v; v.i = ((unsigned int)u) << 16; return v.f;
}
// Compiler-native conversion (RNE): pairs get packed into v_cvt_pk_bf16_f32.
__device__ inline unsigned short f2bf(float f) {
    union { __hip_bfloat16 h; unsigned short u; } v;
    v.h = __float2bfloat16(f);
    return v.u;
}

// async global->LDS, 16B per lane, linear dest (wave-uniform base + lane*16)
__device__ inline void load_lds16(const void* g, void* l) {
    __builtin_amdgcn_global_load_lds(
        (const __attribute__((address_space(1))) void*)g,
        (__attribute__((address_space(3))) void*)l, 16, 0, 0);
}

// ---------------------------------------------------------------------------
// Depthwise 3x3 conv + BN. Block = (b_l, ic); filter/BN consts block-uniform.
// 448 threads; thread t < 392 owns one 8-wide group; n0 = 8t (coalesced).
// ---------------------------------------------------------------------------
__global__ __launch_bounds__(448) void conv_bn_kernel(
    const float* __restrict__ x, const float* __restrict__ cw,
    const float* __restrict__ gamma, const float* __restrict__ beta,
    const float* __restrict__ mean, const float* __restrict__ var,
    bf16* __restrict__ qkdst, bf16* __restrict__ vdst, int b0)
{
    int bid = blockIdx.x;                 // nb*C_
    int ic = bid & 511; int b_l = bid >> 9;
    int b = b0 + b_l;
    const float* xin = x + ((size_t)b * C_ + ic) * N_;

    float w9[3][9], inv3[3], bias3[3];
#pragma unroll
    for (int t = 0; t < 3; ++t) {
        int o = ic * 3 + t;
#pragma unroll
        for (int k = 0; k < 9; ++k) w9[t][k] = cw[o * 9 + k];
        float iv = gamma[o] * rsqrtf(var[o] + 1e-5f);
        inv3[t] = iv;
        bias3[t] = fmaf(-mean[o], iv, beta[o]);
    }

    int t = threadIdx.x;
    if (t < 392) {
        int yy = t / 7;
        int xx0 = (t - yy * 7) * 8;
        int n0 = t * 8;                   // == yy*56 + xx0
        float vin[3][10];
#pragma unroll
        for (int dy = 0; dy < 3; ++dy) {
            int y2 = yy + dy - 1;
            bool rowok = (y2 >= 0) && (y2 < H_);
            const float* rp = xin + y2 * W_ + xx0;
            if (rowok) {
                float4 a = *(const float4*)rp;
                float4 c4 = *(const float4*)(rp + 4);
                vin[dy][1] = a.x;  vin[dy][2] = a.y;  vin[dy][3] = a.z;  vin[dy][4] = a.w;
                vin[dy][5] = c4.x; vin[dy][6] = c4.y; vin[dy][7] = c4.z; vin[dy][8] = c4.w;
                vin[dy][0] = (xx0 > 0)  ? rp[-1] : 0.f;
                vin[dy][9] = (xx0 < 48) ? rp[8]  : 0.f;
            } else {
#pragma unroll
                for (int j = 0; j < 10; ++j) vin[dy][j] = 0.f;
            }
        }
#pragma unroll
        for (int ft = 0; ft < 3; ++ft) {
            int o = ic * 3 + ft;          // uniform
            int s = o >> 9;               // uniform
            int c = o & 511;
            float r[8];
#pragma unroll
            for (int j = 0; j < 8; ++j) {
                float acc = 0.f;
#pragma unroll
                for (int ky = 0; ky < 3; ++ky)
#pragma unroll
                    for (int kx = 0; kx < 3; ++kx)
                        acc = fmaf(vin[ky][j + kx], w9[ft][ky*3+kx], acc);
                r[j] = fmaf(acc, inv3[ft], bias3[ft]);
            }
            short8 r8;
#pragma unroll
            for (int j = 0; j < 8; ++j) r8[j] = (short)f2bf(r[j]);
            bf16* dst = (s < 2)
                ? qkdst + (((size_t)b_l * 2 + s) * C_ + c) * N_
                : vdst + ((size_t)b_l * C_ + c) * N_;
            *(short8*)(dst + n0) = r8;
        }
    }
}

// ---------------------------------------------------------------------------
// Gram partials via MFMA (T2 swizzle + gload_lds):
//   part[s][bh][d*64+e] = sum_{n in split s} q[d,n]*k[e,n]
// ---------------------------------------------------------------------------
__global__ __launch_bounds__(256) void gram_mfma_kernel(
    const bf16* __restrict__ qk, float* __restrict__ part, int bhTot)
{
    __shared__ bf16 qs[64 * 64];
    __shared__ bf16 ks[64 * 64];
    int bid = blockIdx.x;                 // bhTot*SPLIT
    int s = bid % SPLIT; int bh = bid / SPLIT;
    int h = bh % NH; int b_l = bh / NH;
    const bf16* qp = qk + (((size_t)b_l * 2 + 0) * C_ + h * HD) * N_;
    const bf16* kp = qk + (((size_t)b_l * 2 + 1) * C_ + h * HD) * N_;
    int t = threadIdx.x;
    int w = t >> 6, l = t & 63;
    int r16 = l & 15, kg = l >> 4;
    int wr = w >> 1, wc = w & 1;
    int rsub = l >> 3;
    int colp = ((l & 7) ^ rsub) * 8;      // pre-swizzled n-element offset
    int n0 = s * (N_ / SPLIT);

    f32x4 acc[2][2];
#pragma unroll
    for (int i = 0; i < 2; ++i)
#pragma unroll
        for (int j = 0; j < 2; ++j) acc[i][j] = (f32x4){0.f, 0.f, 0.f, 0.f};

    for (int nc = 0; nc < N_ / SPLIT; nc += 64) {
        int nb = n0 + nc;
#pragma unroll
        for (int i = 0; i < 2; ++i) {
            int row = i * 32 + w * 8 + rsub;
            load_lds16(qp + (size_t)row * N_ + nb + colp, (char*)qs + i * 4096 + t * 16);
            load_lds16(kp + (size_t)row * N_ + nb + colp, (char*)ks + i * 4096 + t * 16);
        }
        __syncthreads();
#pragma unroll
        for (int ksb = 0; ksb < 2; ++ksb) {
            short8 af[2], bfv[2];
#pragma unroll
            for (int mi = 0; mi < 2; ++mi) {
                int row = wr * 32 + mi * 16 + r16;
                int off = row * 128 + ((ksb * 64 + kg * 16) ^ ((row & 7) << 4));
                af[mi] = *(const short8*)((const char*)qs + off);
            }
#pragma unroll
            for (int nj = 0; nj < 2; ++nj) {
                int row = wc * 32 + nj * 16 + r16;
                int off = row * 128 + ((ksb * 64 + kg * 16) ^ ((row & 7) << 4));
                bfv[nj] = *(const short8*)((const char*)ks + off);
            }
#pragma unroll
            for (int mi = 0; mi < 2; ++mi)
#pragma unroll
                for (int nj = 0; nj < 2; ++nj)
                    acc[mi][nj] = __builtin_amdgcn_mfma_f32_16x16x32_bf16(
                        af[mi], bfv[nj], acc[mi][nj], 0, 0, 0);
        }
        __syncthreads();
    }
    float* pp = part + ((size_t)s * bhTot + bh) * 4096;
#pragma unroll
    for (int mi = 0; mi < 2; ++mi)
#pragma unroll
        for (int nj = 0; nj < 2; ++nj) {
            int e = wc * 32 + nj * 16 + r16;
#pragma unroll
            for (int r = 0; r < 4; ++r) {
                int d = wr * 32 + mi * 16 + kg * 4 + r;
                pp[d * 64 + e] = acc[mi][nj][r];
            }
        }
}

// ---------------------------------------------------------------------------
// Reduce partials, scale, softmax over e. One wave per (bh,d) row.
// Writes P TRANSPOSED: PT[bh][e*64+d].
// ---------------------------------------------------------------------------
__global__ __launch_bounds__(64) void softmax_kernel(
    const float* __restrict__ part, float* __restrict__ PT, int bhTot)
{
    int row = blockIdx.x;                 // bh*64 + d
    int e = threadIdx.x;
    size_t base = (size_t)row * 64 + e;
    float val = 0.f;
#pragma unroll
    for (int s = 0; s < SPLIT; ++s) val += part[(size_t)s * bhTot * 4096 + base];
    val *= 0.125f;                        // hd^-0.5
    float m = val;
#pragma unroll
    for (int off = 32; off > 0; off >>= 1) m = fmaxf(m, __shfl_xor(m, off));
    float ex = expf(val - m);
    float sum = ex;
#pragma unroll
    for (int off = 32; off > 0; off >>= 1) sum += __shfl_xor(sum, off);
    PT[(size_t)(row >> 6) * 4096 + (size_t)e * 64 + (row & 63)] = ex / sum;
}

// ---------------------------------------------------------------------------
// outA[b_l][d][h][n] = sum_e PT[e][d] * v[b_l][h*64+e][n]   (bf16 out)
// ---------------------------------------------------------------------------
__global__ __launch_bounds__(256) void pv_kernel(
    const bf16* __restrict__ v, const float* __restrict__ PT,
    bf16* __restrict__ outA)
{
    __shared__ float pts[4096];           // PT[e][d] 16KB
    __shared__ bf16 vs[64 * 64];          // vs[e][n] 8KB
    int bid = blockIdx.x;                 // bhTot*49
    int nt = bid % 49; int bh = bid / 49;
    int h = bh % NH, b_l = bh / NH;
    int t = threadIdx.x;
    const float* ptg = PT + (size_t)bh * 4096;
#pragma unroll
    for (int i = 0; i < 4; ++i)
        load_lds16(ptg + i * 1024 + t * 4, (char*)pts + i * 4096 + t * 16);
    const bf16* vb = v + ((size_t)b_l * C_ + h * HD) * N_ + nt * 64;
#pragma unroll
    for (int i = 0; i < 2; ++i) {
        int row = i * 32 + (t >> 3);
        load_lds16(vb + (size_t)row * N_ + (t & 7) * 8, (char*)vs + i * 4096 + t * 16);
    }
    __syncthreads();

    int ng = t & 15, dg = t >> 4;         // n0 = ng*4, d0 = dg*4
    float acc[4][4] = {};
#pragma unroll 16
    for (int e = 0; e < 64; ++e) {
        float4 p = *(const float4*)&pts[e * 64 + dg * 4];
        ushort4 vv = *(const ushort4*)&vs[e * 64 + ng * 4];
        float v0 = bf2f(vv.x), v1 = bf2f(vv.y), v2 = bf2f(vv.z), v3 = bf2f(vv.w);
        float p4[4] = {p.x, p.y, p.z, p.w};
#pragma unroll
        for (int i = 0; i < 4; ++i) {
            acc[i][0] = fmaf(p4[i], v0, acc[i][0]);
            acc[i][1] = fmaf(p4[i], v1, acc[i][1]);
            acc[i][2] = fmaf(p4[i], v2, acc[i][2]);
            acc[i][3] = fmaf(p4[i], v3, acc[i][3]);
        }
    }
    bf16* op = outA + (size_t)b_l * (C_*N_) + (size_t)h * N_ + nt * 64 + ng * 4;
#pragma unroll
    for (int i = 0; i < 4; ++i) {
        ushort4 r4;
        unsigned short* rr = (unsigned short*)&r4;
        rr[0] = f2bf(acc[i][0]); rr[1] = f2bf(acc[i][1]);
        rr[2] = f2bf(acc[i][2]); rr[3] = f2bf(acc[i][3]);
        *(ushort4*)(op + (size_t)(dg * 4 + i) * (NH*N_)) = r4;
    }
}

// ---------------------------------------------------------------------------
// Convert projection weights f32 -> bf16 (512x512).
// ---------------------------------------------------------------------------
__global__ __launch_bounds__(256) void wconv_kernel(
    const float* __restrict__ w, bf16* __restrict__ wb)
{
    int i = blockIdx.x * 256 + threadIdx.x;   // 262144 total
    wb[i] = f2bf(w[i]);
}

// ---------------------------------------------------------------------------
// MFMA projection, 8 waves, tile 128(co) x 256(n), single-buffered LDS
// (16KB W + 32KB A = 48KB -> VGPR-capped 24 waves/CU), XCD-chunked swizzle
// with mt fastest (A-quad on one XCD).
//   out[b0+b_l][co][n] = sum_c Wb[co][c]*A[b_l][n][c] + pb[co]
// ---------------------------------------------------------------------------
__global__ __launch_bounds__(512) void proj_mfma_kernel(
    const bf16* __restrict__ A, const bf16* __restrict__ Wb,
    const float* __restrict__ bias, float* __restrict__ out, int b0, int nwg)
{
    __shared__ bf16 Ws_s[128 * 64];       // 16 KB
    __shared__ bf16 As_s[256 * 64];       // 32 KB
    int bid = blockIdx.x;                 // nwg = nb*52, nwg % 8 == 0
    int cpx = nwg >> 3;                   // chunk per XCD (104: % 4 == 0)
    int swz = (bid & 7) * cpx + (bid >> 3);
    int b_l = swz / 52; int rem = swz % 52;
    int nt = rem >> 2, mt = rem & 3;      // mt fastest: A-quad on one XCD
    int m0 = mt * 128, n0 = nt * 256;     // nt in 0..12 (13*256=3328, pad)
    int t = threadIdx.x;
    int w = t >> 6, l = t & 63;
    int r16 = l & 15, kg = l >> 4;        // frag row / k-group
    int wr = w >> 2, wc = w & 3;          // wave quadrant: 2 co x 4 n
    const bf16* Ab = A + (size_t)b_l * N_ * C_;
    int srow = t >> 3;                    // staging row within 64-row chunk
    int colp = ((t & 7) ^ (srow & 7)) * 8;// pre-swizzled k-element offset

    f32x4 acc[4][4];
#pragma unroll
    for (int i = 0; i < 4; ++i)
#pragma unroll
        for (int j = 0; j < 4; ++j) acc[i][j] = (f32x4){0.f, 0.f, 0.f, 0.f};

    for (int k0 = 0; k0 < C_; k0 += 64) {
        // stage W: 128 rows x 64 k (2 rounds of 64 rows)
#pragma unroll
        for (int i = 0; i < 2; ++i) {
            int row = i * 64 + srow;
            load_lds16(Wb + (size_t)(m0 + row) * C_ + k0 + colp,
                       (char*)Ws_s + i * 8192 + t * 16);
        }
        // stage A: 256 rows x 64 k (4 rounds)
#pragma unroll
        for (int i = 0; i < 4; ++i) {
            int row = i * 64 + srow;
            int nn = n0 + row; if (nn >= N_) nn = N_ - 1;
            load_lds16(Ab + (size_t)nn * C_ + k0 + colp,
                       (char*)As_s + i * 8192 + t * 16);
        }
        __syncthreads();
#pragma unroll
        for (int ks = 0; ks < 2; ++ks) {
            short8 af[4], bfv[4];
#pragma unroll
            for (int mi = 0; mi < 4; ++mi) {
                int row = wr * 64 + mi * 16 + r16;
                int off = row * 128 + ((ks * 64 + kg * 16) ^ ((row & 7) << 4));
                af[mi] = *(const short8*)((const char*)Ws_s + off);
            }
#pragma unroll
            for (int nj = 0; nj < 4; ++nj) {
                int row = wc * 64 + nj * 16 + r16;
                int off = row * 128 + ((ks * 64 + kg * 16) ^ ((row & 7) << 4));
                bfv[nj] = *(const short8*)((const char*)As_s + off);
            }
#pragma unroll
            for (int mi = 0; mi < 4; ++mi)
#pragma unroll
                for (int nj = 0; nj < 4; ++nj)
                    acc[mi][nj] = __builtin_amdgcn_mfma_f32_16x16x32_bf16(
                        af[mi], bfv[nj], acc[mi][nj], 0, 0, 0);
        }
        __syncthreads();
    }
    float* ob = out + ((size_t)(b0 + b_l) * C_) * N_;
#pragma unroll
    for (int mi = 0; mi < 4; ++mi) {
        int cobase = m0 + wr * 64 + mi * 16 + kg * 4;
#pragma unroll
        for (int r = 0; r < 4; ++r) {
            int co = cobase + r;
            float bi = bias[co];
#pragma unroll
            for (int nj = 0; nj < 4; ++nj) {
                int n = n0 + wc * 64 + nj * 16 + r16;
                if (n < N_) ob[(size_t)co * N_ + n] = acc[mi][nj][r] + bi;
            }
        }
    }
}

extern "C" void kernel_launch(void* const* d_in, const int* in_sizes, int n_in,
                              void* d_out, int out_size, void* d_ws, size_t ws_size,
                              hipStream_t stream) {
    const float* x     = (const float*)d_in[0];
    const float* cw    = (const float*)d_in[1];
    const float* gamma = (const float*)d_in[2];
    const float* beta  = (const float*)d_in[3];
    const float* mean  = (const float*)d_in[4];
    const float* var   = (const float*)d_in[5];
    const float* pw    = (const float*)d_in[6];
    const float* pb    = (const float*)d_in[7];
    float* out = (float*)d_out;
    char* wsp = (char*)d_ws;

    const size_t W_B = (size_t)C_ * C_ * sizeof(bf16);              // 524,288

    // Single-pass (all 16 batches) if workspace allows; else two passes of 8.
    size_t qk16   = (size_t)16 * 2 * C_ * N_ * sizeof(bf16);        // 102.8 MB
    size_t v16    = (size_t)16 * C_ * N_ * sizeof(bf16);            //  51.4 MB
    size_t part16 = (size_t)SPLIT * 16 * NH * 4096 * 4;             //  14.7 MB
    size_t pt16   = (size_t)16 * NH * 4096 * 4;                     //   2.1 MB

    int nbs[2]; int ngroups;
    if (ws_size >= qk16 + v16 + part16 + pt16 + W_B) {
        ngroups = 1; nbs[0] = 16;
    } else {
        ngroups = 2; nbs[0] = 8; nbs[1] = 8;
    }

    int b0 = 0;
    for (int gi = 0; gi < ngroups; ++gi) {
        int nb = nbs[gi];
        size_t QK_B   = (size_t)nb * 2 * C_ * N_ * sizeof(bf16);
        size_t V_B    = (size_t)nb * C_ * N_ * sizeof(bf16);
        size_t PART_B = (size_t)SPLIT * nb * NH * 4096 * 4;
        size_t PT_B   = (size_t)nb * NH * 4096 * 4;
        bf16*  qk   = (bf16*)wsp;
        bf16*  v    = (bf16*)(wsp + QK_B);
        float* part = (float*)(wsp + QK_B + V_B);
        float* PT   = (float*)(wsp + QK_B + V_B + PART_B);
        bf16*  Wbf  = (bf16*)(wsp + QK_B + V_B + PART_B + PT_B);
        bf16*  outA = qk;                  // reuse q,k region after gram
        int bhTot = nb * NH;

        if (gi == 0)
            wconv_kernel<<<(C_ * C_) / 256, 256, 0, stream>>>(pw, Wbf);

        conv_bn_kernel<<<nb * C_, 448, 0, stream>>>(
            x, cw, gamma, beta, mean, var, qk, v, b0);
        gram_mfma_kernel<<<bhTot * SPLIT, 256, 0, stream>>>(qk, part, bhTot);
        softmax_kernel<<<bhTot * 64, 64, 0, stream>>>(part, PT, bhTot);
        pv_kernel<<<bhTot * 49, 256, 0, stream>>>(v, PT, outA);
        proj_mfma_kernel<<<nb * 52, 512, 0, stream>>>(outA, Wbf, pb, out, b0, nb * 52);
        b0 += nb;
    }
}

// Round 16
// 190.609 us; speedup vs baseline: 1.2586x; 1.0290x over previous
//
#include <hip/hip_runtime.h>
#include <hip/hip_bf16.h>
#include <math.h>

#define B_ 16
#define C_ 512
#define H_ 56
#define W_ 56
#define N_ 3136          // H_*W_ = 49*64
#define NH 8
#define HD 64
#define SPLIT 7          // n-split for gram; 3136/7 = 448

typedef unsigned short bf16;
typedef __attribute__((ext_vector_type(8))) short short8;
typedef __attribute__((ext_vector_type(4))) float f32x4;

__device__ inline float bf2f(unsigned short u) {
    union { unsigned int i; float f; } v; v.i = ((unsigned int)u) << 16; return v.f;
}
// Compiler-native conversion (RNE): pairs get packed into v_cvt_pk_bf16_f32.
__device__ inline unsigned short f2bf(float f) {
    union { __hip_bfloat16 h; unsigned short u; } v;
    v.h = __float2bfloat16(f);
    return v.u;
}

// async global->LDS, 16B per lane, linear dest (wave-uniform base + lane*16)
__device__ inline void load_lds16(const void* g, void* l) {
    __builtin_amdgcn_global_load_lds(
        (const __attribute__((address_space(1))) void*)g,
        (__attribute__((address_space(3))) void*)l, 16, 0, 0);
}

// ---------------------------------------------------------------------------
// Depthwise 3x3 conv + BN. Block = (b_l, ic); filter/BN consts block-uniform.
// 448 threads; thread t < 392 owns one 8-wide group; n0 = 8t (coalesced).
// ---------------------------------------------------------------------------
__global__ __launch_bounds__(448) void conv_bn_kernel(
    const float* __restrict__ x, const float* __restrict__ cw,
    const float* __restrict__ gamma, const float* __restrict__ beta,
    const float* __restrict__ mean, const float* __restrict__ var,
    bf16* __restrict__ qkdst, bf16* __restrict__ vdst, int b0)
{
    int bid = blockIdx.x;                 // nb*C_
    int ic = bid & 511; int b_l = bid >> 9;
    int b = b0 + b_l;
    const float* xin = x + ((size_t)b * C_ + ic) * N_;

    float w9[3][9], inv3[3], bias3[3];
#pragma unroll
    for (int t = 0; t < 3; ++t) {
        int o = ic * 3 + t;
#pragma unroll
        for (int k = 0; k < 9; ++k) w9[t][k] = cw[o * 9 + k];
        float iv = gamma[o] * rsqrtf(var[o] + 1e-5f);
        inv3[t] = iv;
        bias3[t] = fmaf(-mean[o], iv, beta[o]);
    }

    int t = threadIdx.x;
    if (t < 392) {
        int yy = t / 7;
        int xx0 = (t - yy * 7) * 8;
        int n0 = t * 8;                   // == yy*56 + xx0
        float vin[3][10];
#pragma unroll
        for (int dy = 0; dy < 3; ++dy) {
            int y2 = yy + dy - 1;
            bool rowok = (y2 >= 0) && (y2 < H_);
            const float* rp = xin + y2 * W_ + xx0;
            if (rowok) {
                float4 a = *(const float4*)rp;
                float4 c4 = *(const float4*)(rp + 4);
                vin[dy][1] = a.x;  vin[dy][2] = a.y;  vin[dy][3] = a.z;  vin[dy][4] = a.w;
                vin[dy][5] = c4.x; vin[dy][6] = c4.y; vin[dy][7] = c4.z; vin[dy][8] = c4.w;
                vin[dy][0] = (xx0 > 0)  ? rp[-1] : 0.f;
                vin[dy][9] = (xx0 < 48) ? rp[8]  : 0.f;
            } else {
#pragma unroll
                for (int j = 0; j < 10; ++j) vin[dy][j] = 0.f;
            }
        }
#pragma unroll
        for (int ft = 0; ft < 3; ++ft) {
            int o = ic * 3 + ft;          // uniform
            int s = o >> 9;               // uniform
            int c = o & 511;
            float r[8];
#pragma unroll
            for (int j = 0; j < 8; ++j) {
                float acc = 0.f;
#pragma unroll
                for (int ky = 0; ky < 3; ++ky)
#pragma unroll
                    for (int kx = 0; kx < 3; ++kx)
                        acc = fmaf(vin[ky][j + kx], w9[ft][ky*3+kx], acc);
                r[j] = fmaf(acc, inv3[ft], bias3[ft]);
            }
            short8 r8;
#pragma unroll
            for (int j = 0; j < 8; ++j) r8[j] = (short)f2bf(r[j]);
            bf16* dst = (s < 2)
                ? qkdst + (((size_t)b_l * 2 + s) * C_ + c) * N_
                : vdst + ((size_t)b_l * C_ + c) * N_;
            *(short8*)(dst + n0) = r8;
        }
    }
}

// ---------------------------------------------------------------------------
// Gram partials via MFMA (T2 swizzle + gload_lds):
//   part[s][bh][d*64+e] = sum_{n in split s} q[d,n]*k[e,n]
// ---------------------------------------------------------------------------
__global__ __launch_bounds__(256) void gram_mfma_kernel(
    const bf16* __restrict__ qk, float* __restrict__ part, int bhTot)
{
    __shared__ bf16 qs[64 * 64];
    __shared__ bf16 ks[64 * 64];
    int bid = blockIdx.x;                 // bhTot*SPLIT
    int s = bid % SPLIT; int bh = bid / SPLIT;
    int h = bh % NH; int b_l = bh / NH;
    const bf16* qp = qk + (((size_t)b_l * 2 + 0) * C_ + h * HD) * N_;
    const bf16* kp = qk + (((size_t)b_l * 2 + 1) * C_ + h * HD) * N_;
    int t = threadIdx.x;
    int w = t >> 6, l = t & 63;
    int r16 = l & 15, kg = l >> 4;
    int wr = w >> 1, wc = w & 1;
    int rsub = l >> 3;
    int colp = ((l & 7) ^ rsub) * 8;      // pre-swizzled n-element offset
    int n0 = s * (N_ / SPLIT);

    f32x4 acc[2][2];
#pragma unroll
    for (int i = 0; i < 2; ++i)
#pragma unroll
        for (int j = 0; j < 2; ++j) acc[i][j] = (f32x4){0.f, 0.f, 0.f, 0.f};

    for (int nc = 0; nc < N_ / SPLIT; nc += 64) {
        int nb = n0 + nc;
#pragma unroll
        for (int i = 0; i < 2; ++i) {
            int row = i * 32 + w * 8 + rsub;
            load_lds16(qp + (size_t)row * N_ + nb + colp, (char*)qs + i * 4096 + t * 16);
            load_lds16(kp + (size_t)row * N_ + nb + colp, (char*)ks + i * 4096 + t * 16);
        }
        __syncthreads();
#pragma unroll
        for (int ksb = 0; ksb < 2; ++ksb) {
            short8 af[2], bfv[2];
#pragma unroll
            for (int mi = 0; mi < 2; ++mi) {
                int row = wr * 32 + mi * 16 + r16;
                int off = row * 128 + ((ksb * 64 + kg * 16) ^ ((row & 7) << 4));
                af[mi] = *(const short8*)((const char*)qs + off);
            }
#pragma unroll
            for (int nj = 0; nj < 2; ++nj) {
                int row = wc * 32 + nj * 16 + r16;
                int off = row * 128 + ((ksb * 64 + kg * 16) ^ ((row & 7) << 4));
                bfv[nj] = *(const short8*)((const char*)ks + off);
            }
#pragma unroll
            for (int mi = 0; mi < 2; ++mi)
#pragma unroll
                for (int nj = 0; nj < 2; ++nj)
                    acc[mi][nj] = __builtin_amdgcn_mfma_f32_16x16x32_bf16(
                        af[mi], bfv[nj], acc[mi][nj], 0, 0, 0);
        }
        __syncthreads();
    }
    float* pp = part + ((size_t)s * bhTot + bh) * 4096;
#pragma unroll
    for (int mi = 0; mi < 2; ++mi)
#pragma unroll
        for (int nj = 0; nj < 2; ++nj) {
            int e = wc * 32 + nj * 16 + r16;
#pragma unroll
            for (int r = 0; r < 4; ++r) {
                int d = wr * 32 + mi * 16 + kg * 4 + r;
                pp[d * 64 + e] = acc[mi][nj][r];
            }
        }
}

// ---------------------------------------------------------------------------
// Reduce partials, scale, softmax over e. One wave per (bh,d) row.
// Writes P TRANSPOSED: PT[bh][e*64+d].
// ---------------------------------------------------------------------------
__global__ __launch_bounds__(64) void softmax_kernel(
    const float* __restrict__ part, float* __restrict__ PT, int bhTot)
{
    int row = blockIdx.x;                 // bh*64 + d
    int e = threadIdx.x;
    size_t base = (size_t)row * 64 + e;
    float val = 0.f;
#pragma unroll
    for (int s = 0; s < SPLIT; ++s) val += part[(size_t)s * bhTot * 4096 + base];
    val *= 0.125f;                        // hd^-0.5
    float m = val;
#pragma unroll
    for (int off = 32; off > 0; off >>= 1) m = fmaxf(m, __shfl_xor(m, off));
    float ex = expf(val - m);
    float sum = ex;
#pragma unroll
    for (int off = 32; off > 0; off >>= 1) sum += __shfl_xor(sum, off);
    PT[(size_t)(row >> 6) * 4096 + (size_t)e * 64 + (row & 63)] = ex / sum;
}

// ---------------------------------------------------------------------------
// outA[b_l][d][h][n] = sum_e PT[e][d] * v[b_l][h*64+e][n]   (bf16 out)
// 128-px tile per block: PT (16KB) staged once serves 2x the output
// (PT traffic halved vs 64-px tiles). Thread = 8d x 4n patch.
// ---------------------------------------------------------------------------
__global__ __launch_bounds__(256) void pv_kernel(
    const bf16* __restrict__ v, const float* __restrict__ PT,
    bf16* __restrict__ outA)
{
    __shared__ float pts[4096];           // PT[e][d] 16KB
    __shared__ bf16 vs[64 * 128];         // vs[e][n] 16KB
    int bid = blockIdx.x;                 // bhTot*25
    int nt = bid % 25; int bh = bid / 25;
    int h = bh % NH, b_l = bh / NH;
    int t = threadIdx.x;
    int nbase = nt * 128;                 // nt=24 tile is partial (3072..3135)
    const float* ptg = PT + (size_t)bh * 4096;
#pragma unroll
    for (int i = 0; i < 4; ++i)
        load_lds16(ptg + i * 1024 + t * 4, (char*)pts + i * 4096 + t * 16);
    const bf16* vb = v + ((size_t)b_l * C_ + h * HD) * N_;
#pragma unroll
    for (int i = 0; i < 4; ++i) {
        int row = i * 16 + (t >> 4);      // e row 0..63
        int n = nbase + (t & 15) * 8;
        if (n > N_ - 8) n = N_ - 8;       // clamp source (dup cols unused)
        // dest byte = i*4096 + (t>>4)*256 + (t&15)*16 == wave-linear lane*16
        load_lds16(vb + (size_t)row * N_ + n,
                   (char*)vs + i * 4096 + (t >> 4) * 256 + (t & 15) * 16);
    }
    __syncthreads();

    int ng = t & 31, dg = t >> 5;         // n-sub = ng*4 (0..127), d0 = dg*8
    float acc[8][4] = {};
#pragma unroll 8
    for (int e = 0; e < 64; ++e) {
        float4 p0 = *(const float4*)&pts[e * 64 + dg * 8];
        float4 p1 = *(const float4*)&pts[e * 64 + dg * 8 + 4];
        ushort4 vv = *(const ushort4*)&vs[e * 128 + ng * 4];
        float v0 = bf2f(vv.x), v1 = bf2f(vv.y), v2 = bf2f(vv.z), v3 = bf2f(vv.w);
        float p8[8] = {p0.x, p0.y, p0.z, p0.w, p1.x, p1.y, p1.z, p1.w};
#pragma unroll
        for (int i = 0; i < 8; ++i) {
            acc[i][0] = fmaf(p8[i], v0, acc[i][0]);
            acc[i][1] = fmaf(p8[i], v1, acc[i][1]);
            acc[i][2] = fmaf(p8[i], v2, acc[i][2]);
            acc[i][3] = fmaf(p8[i], v3, acc[i][3]);
        }
    }
    if (nbase + ng * 4 < N_) {            // 4-aligned, N_ % 4 == 0
        bf16* op = outA + (size_t)b_l * (C_*N_) + (size_t)h * N_ + nbase + ng * 4;
#pragma unroll
        for (int i = 0; i < 8; ++i) {
            ushort4 r4;
            unsigned short* rr = (unsigned short*)&r4;
            rr[0] = f2bf(acc[i][0]); rr[1] = f2bf(acc[i][1]);
            rr[2] = f2bf(acc[i][2]); rr[3] = f2bf(acc[i][3]);
            *(ushort4*)(op + (size_t)(dg * 8 + i) * (NH*N_)) = r4;
        }
    }
}

// ---------------------------------------------------------------------------
// Convert projection weights f32 -> bf16 (512x512).
// ---------------------------------------------------------------------------
__global__ __launch_bounds__(256) void wconv_kernel(
    const float* __restrict__ w, bf16* __restrict__ wb)
{
    int i = blockIdx.x * 256 + threadIdx.x;   // 262144 total
    wb[i] = f2bf(w[i]);
}

// ---------------------------------------------------------------------------
// MFMA projection, 8 waves, tile 128(co) x 256(n), single-buffered LDS
// (48KB), XCD-chunked swizzle with mt fastest.
//   out[b0+b_l][co][n] = sum_c Wb[co][c]*A[b_l][n][c] + pb[co]
// ---------------------------------------------------------------------------
__global__ __launch_bounds__(512) void proj_mfma_kernel(
    const bf16* __restrict__ A, const bf16* __restrict__ Wb,
    const float* __restrict__ bias, float* __restrict__ out, int b0, int nwg)
{
    __shared__ bf16 Ws_s[128 * 64];       // 16 KB
    __shared__ bf16 As_s[256 * 64];       // 32 KB
    int bid = blockIdx.x;                 // nwg = nb*52, nwg % 8 == 0
    int cpx = nwg >> 3;                   // chunk per XCD (104: % 4 == 0)
    int swz = (bid & 7) * cpx + (bid >> 3);
    int b_l = swz / 52; int rem = swz % 52;
    int nt = rem >> 2, mt = rem & 3;      // mt fastest: A-quad on one XCD
    int m0 = mt * 128, n0 = nt * 256;     // nt in 0..12
    int t = threadIdx.x;
    int w = t >> 6, l = t & 63;
    int r16 = l & 15, kg = l >> 4;        // frag row / k-group
    int wr = w >> 2, wc = w & 3;          // wave quadrant: 2 co x 4 n
    const bf16* Ab = A + (size_t)b_l * N_ * C_;
    int srow = t >> 3;                    // staging row within 64-row chunk
    int colp = ((t & 7) ^ (srow & 7)) * 8;// pre-swizzled k-element offset

    f32x4 acc[4][4];
#pragma unroll
    for (int i = 0; i < 4; ++i)
#pragma unroll
        for (int j = 0; j < 4; ++j) acc[i][j] = (f32x4){0.f, 0.f, 0.f, 0.f};

    for (int k0 = 0; k0 < C_; k0 += 64) {
#pragma unroll
        for (int i = 0; i < 2; ++i) {
            int row = i * 64 + srow;
            load_lds16(Wb + (size_t)(m0 + row) * C_ + k0 + colp,
                       (char*)Ws_s + i * 8192 + t * 16);
        }
#pragma unroll
        for (int i = 0; i < 4; ++i) {
            int row = i * 64 + srow;
            int nn = n0 + row; if (nn >= N_) nn = N_ - 1;
            load_lds16(Ab + (size_t)nn * C_ + k0 + colp,
                       (char*)As_s + i * 8192 + t * 16);
        }
        __syncthreads();
#pragma unroll
        for (int ks = 0; ks < 2; ++ks) {
            short8 af[4], bfv[4];
#pragma unroll
            for (int mi = 0; mi < 4; ++mi) {
                int row = wr * 64 + mi * 16 + r16;
                int off = row * 128 + ((ks * 64 + kg * 16) ^ ((row & 7) << 4));
                af[mi] = *(const short8*)((const char*)Ws_s + off);
            }
#pragma unroll
            for (int nj = 0; nj < 4; ++nj) {
                int row = wc * 64 + nj * 16 + r16;
                int off = row * 128 + ((ks * 64 + kg * 16) ^ ((row & 7) << 4));
                bfv[nj] = *(const short8*)((const char*)As_s + off);
            }
#pragma unroll
            for (int mi = 0; mi < 4; ++mi)
#pragma unroll
                for (int nj = 0; nj < 4; ++nj)
                    acc[mi][nj] = __builtin_amdgcn_mfma_f32_16x16x32_bf16(
                        af[mi], bfv[nj], acc[mi][nj], 0, 0, 0);
        }
        __syncthreads();
    }
    float* ob = out + ((size_t)(b0 + b_l) * C_) * N_;
#pragma unroll
    for (int mi = 0; mi < 4; ++mi) {
        int cobase = m0 + wr * 64 + mi * 16 + kg * 4;
#pragma unroll
        for (int r = 0; r < 4; ++r) {
            int co = cobase + r;
            float bi = bias[co];
#pragma unroll
            for (int nj = 0; nj < 4; ++nj) {
                int n = n0 + wc * 64 + nj * 16 + r16;
                if (n < N_) ob[(size_t)co * N_ + n] = acc[mi][nj][r] + bi;
            }
        }
    }
}

extern "C" void kernel_launch(void* const* d_in, const int* in_sizes, int n_in,
                              void* d_out, int out_size, void* d_ws, size_t ws_size,
                              hipStream_t stream) {
    const float* x     = (const float*)d_in[0];
    const float* cw    = (const float*)d_in[1];
    const float* gamma = (const float*)d_in[2];
    const float* beta  = (const float*)d_in[3];
    const float* mean  = (const float*)d_in[4];
    const float* var   = (const float*)d_in[5];
    const float* pw    = (const float*)d_in[6];
    const float* pb    = (const float*)d_in[7];
    float* out = (float*)d_out;
    char* wsp = (char*)d_ws;

    const size_t W_B = (size_t)C_ * C_ * sizeof(bf16);              // 524,288

    // Single-pass (all 16 batches) if workspace allows; else two passes of 8.
    size_t qk16   = (size_t)16 * 2 * C_ * N_ * sizeof(bf16);        // 102.8 MB
    size_t v16    = (size_t)16 * C_ * N_ * sizeof(bf16);            //  51.4 MB
    size_t part16 = (size_t)SPLIT * 16 * NH * 4096 * 4;             //  14.7 MB
    size_t pt16   = (size_t)16 * NH * 4096 * 4;                     //   2.1 MB

    int nbs[2]; int ngroups;
    if (ws_size >= qk16 + v16 + part16 + pt16 + W_B) {
        ngroups = 1; nbs[0] = 16;
    } else {
        ngroups = 2; nbs[0] = 8; nbs[1] = 8;
    }

    int b0 = 0;
    for (int gi = 0; gi < ngroups; ++gi) {
        int nb = nbs[gi];
        size_t QK_B   = (size_t)nb * 2 * C_ * N_ * sizeof(bf16);
        size_t V_B    = (size_t)nb * C_ * N_ * sizeof(bf16);
        size_t PART_B = (size_t)SPLIT * nb * NH * 4096 * 4;
        size_t PT_B   = (size_t)nb * NH * 4096 * 4;
        bf16*  qk   = (bf16*)wsp;
        bf16*  v    = (bf16*)(wsp + QK_B);
        float* part = (float*)(wsp + QK_B + V_B);
        float* PT   = (float*)(wsp + QK_B + V_B + PART_B);
        bf16*  Wbf  = (bf16*)(wsp + QK_B + V_B + PART_B + PT_B);
        bf16*  outA = qk;                  // reuse q,k region after gram
        int bhTot = nb * NH;

        if (gi == 0)
            wconv_kernel<<<(C_ * C_) / 256, 256, 0, stream>>>(pw, Wbf);

        conv_bn_kernel<<<nb * C_, 448, 0, stream>>>(
            x, cw, gamma, beta, mean, var, qk, v, b0);
        gram_mfma_kernel<<<bhTot * SPLIT, 256, 0, stream>>>(qk, part, bhTot);
        softmax_kernel<<<bhTot * 64, 64, 0, stream>>>(part, PT, bhTot);
        pv_kernel<<<bhTot * 25, 256, 0, stream>>>(v, PT, outA);
        proj_mfma_kernel<<<nb * 52, 512, 0, stream>>>(outA, Wbf, pb, out, b0, nb * 52);
        b0 += nb;
    }
}

// Round 17
// 182.153 us; speedup vs baseline: 1.3171x; 1.0464x over previous
//
#include <hip/hip_runtime.h>
#include <hip/hip_bf16.h>
#include <math.h>

#define B_ 16
#define C_ 512
#define H_ 56
#define W_ 56
#define N_ 3136          // H_*W_ = 49*64
#define NH 8
#define HD 64
#define SPLIT 7          // n-split for gram; 3136/7 = 448

typedef unsigned short bf16;
typedef __attribute__((ext_vector_type(8))) short short8;
typedef __attribute__((ext_vector_type(4))) float f32x4;

__device__ inline float bf2f(unsigned short u) {
    union { unsigned int i; float f; } v; v.i = ((unsigned int)u) << 16; return v.f;
}
// Compiler-native conversion (RNE): pairs get packed into v_cvt_pk_bf16_f32.
__device__ inline unsigned short f2bf(float f) {
    union { __hip_bfloat16 h; unsigned short u; } v;
    v.h = __float2bfloat16(f);
    return v.u;
}

// async global->LDS, 16B per lane, linear dest (wave-uniform base + lane*16)
__device__ inline void load_lds16(const void* g, void* l) {
    __builtin_amdgcn_global_load_lds(
        (const __attribute__((address_space(1))) void*)g,
        (__attribute__((address_space(3))) void*)l, 16, 0, 0);
}

// ---------------------------------------------------------------------------
// Depthwise 3x3 conv + BN. Block = (b_l, ic). The block's entire 12.5 KB
// x-plane is staged into LDS via async global_load_lds (2 rounds of 16B
// chunks), then each thread computes its 8-px group purely from LDS —
// global loads per thread drop 12 -> 2 and are latency-free (async).
// ---------------------------------------------------------------------------
__global__ __launch_bounds__(448) void conv_bn_kernel(
    const float* __restrict__ x, const float* __restrict__ cw,
    const float* __restrict__ gamma, const float* __restrict__ beta,
    const float* __restrict__ mean, const float* __restrict__ var,
    bf16* __restrict__ qkdst, bf16* __restrict__ vdst, int b0)
{
    __shared__ float xs[N_];              // 12,544 B
    int bid = blockIdx.x;                 // nb*C_
    int ic = bid & 511; int b_l = bid >> 9;
    int b = b0 + b_l;
    const float* xin = x + ((size_t)b * C_ + ic) * N_;
    int t = threadIdx.x;

    // stage x-plane: 784 chunks of 16B; round 0 = chunks 0..447, round 1 = 448..783
    load_lds16(xin + t * 4, (char*)xs + t * 16);
    if (t < 336)
        load_lds16(xin + (448 + t) * 4, (char*)xs + 7168 + t * 16);

    // block-uniform filter + BN constants (scalar loads, overlap the staging)
    float w9[3][9], inv3[3], bias3[3];
#pragma unroll
    for (int ft = 0; ft < 3; ++ft) {
        int o = ic * 3 + ft;
#pragma unroll
        for (int k = 0; k < 9; ++k) w9[ft][k] = cw[o * 9 + k];
        float iv = gamma[o] * rsqrtf(var[o] + 1e-5f);
        inv3[ft] = iv;
        bias3[ft] = fmaf(-mean[o], iv, beta[o]);
    }
    __syncthreads();                      // drains gload_lds (vmcnt in barrier)

    if (t < 392) {
        int yy = t / 7;
        int xx0 = (t - yy * 7) * 8;
        int n0 = t * 8;                   // == yy*56 + xx0
        float vin[3][10];
#pragma unroll
        for (int dy = 0; dy < 3; ++dy) {
            int y2 = yy + dy - 1;
            if (y2 >= 0 && y2 < H_) {
                const float* rp = &xs[y2 * W_ + xx0];   // 8B-aligned
                float2 a0 = *(const float2*)(rp + 0);
                float2 a1 = *(const float2*)(rp + 2);
                float2 a2 = *(const float2*)(rp + 4);
                float2 a3 = *(const float2*)(rp + 6);
                vin[dy][1] = a0.x; vin[dy][2] = a0.y;
                vin[dy][3] = a1.x; vin[dy][4] = a1.y;
                vin[dy][5] = a2.x; vin[dy][6] = a2.y;
                vin[dy][7] = a3.x; vin[dy][8] = a3.y;
                vin[dy][0] = (xx0 > 0)  ? rp[-1] : 0.f;
                vin[dy][9] = (xx0 < 48) ? rp[8]  : 0.f;
            } else {
#pragma unroll
                for (int j = 0; j < 10; ++j) vin[dy][j] = 0.f;
            }
        }
#pragma unroll
        for (int ft = 0; ft < 3; ++ft) {
            int o = ic * 3 + ft;          // uniform
            int s = o >> 9;               // uniform
            int c = o & 511;
            float r[8];
#pragma unroll
            for (int j = 0; j < 8; ++j) {
                float acc = 0.f;
#pragma unroll
                for (int ky = 0; ky < 3; ++ky)
#pragma unroll
                    for (int kx = 0; kx < 3; ++kx)
                        acc = fmaf(vin[ky][j + kx], w9[ft][ky*3+kx], acc);
                r[j] = fmaf(acc, inv3[ft], bias3[ft]);
            }
            short8 r8;
#pragma unroll
            for (int j = 0; j < 8; ++j) r8[j] = (short)f2bf(r[j]);
            bf16* dst = (s < 2)
                ? qkdst + (((size_t)b_l * 2 + s) * C_ + c) * N_
                : vdst + ((size_t)b_l * C_ + c) * N_;
            *(short8*)(dst + n0) = r8;
        }
    }
}

// ---------------------------------------------------------------------------
// Gram partials via MFMA (T2 swizzle + gload_lds):
//   part[s][bh][d*64+e] = sum_{n in split s} q[d,n]*k[e,n]
// ---------------------------------------------------------------------------
__global__ __launch_bounds__(256) void gram_mfma_kernel(
    const bf16* __restrict__ qk, float* __restrict__ part, int bhTot)
{
    __shared__ bf16 qs[64 * 64];
    __shared__ bf16 ks[64 * 64];
    int bid = blockIdx.x;                 // bhTot*SPLIT
    int s = bid % SPLIT; int bh = bid / SPLIT;
    int h = bh % NH; int b_l = bh / NH;
    const bf16* qp = qk + (((size_t)b_l * 2 + 0) * C_ + h * HD) * N_;
    const bf16* kp = qk + (((size_t)b_l * 2 + 1) * C_ + h * HD) * N_;
    int t = threadIdx.x;
    int w = t >> 6, l = t & 63;
    int r16 = l & 15, kg = l >> 4;
    int wr = w >> 1, wc = w & 1;
    int rsub = l >> 3;
    int colp = ((l & 7) ^ rsub) * 8;      // pre-swizzled n-element offset
    int n0 = s * (N_ / SPLIT);

    f32x4 acc[2][2];
#pragma unroll
    for (int i = 0; i < 2; ++i)
#pragma unroll
        for (int j = 0; j < 2; ++j) acc[i][j] = (f32x4){0.f, 0.f, 0.f, 0.f};

    for (int nc = 0; nc < N_ / SPLIT; nc += 64) {
        int nb = n0 + nc;
#pragma unroll
        for (int i = 0; i < 2; ++i) {
            int row = i * 32 + w * 8 + rsub;
            load_lds16(qp + (size_t)row * N_ + nb + colp, (char*)qs + i * 4096 + t * 16);
            load_lds16(kp + (size_t)row * N_ + nb + colp, (char*)ks + i * 4096 + t * 16);
        }
        __syncthreads();
#pragma unroll
        for (int ksb = 0; ksb < 2; ++ksb) {
            short8 af[2], bfv[2];
#pragma unroll
            for (int mi = 0; mi < 2; ++mi) {
                int row = wr * 32 + mi * 16 + r16;
                int off = row * 128 + ((ksb * 64 + kg * 16) ^ ((row & 7) << 4));
                af[mi] = *(const short8*)((const char*)qs + off);
            }
#pragma unroll
            for (int nj = 0; nj < 2; ++nj) {
                int row = wc * 32 + nj * 16 + r16;
                int off = row * 128 + ((ksb * 64 + kg * 16) ^ ((row & 7) << 4));
                bfv[nj] = *(const short8*)((const char*)ks + off);
            }
#pragma unroll
            for (int mi = 0; mi < 2; ++mi)
#pragma unroll
                for (int nj = 0; nj < 2; ++nj)
                    acc[mi][nj] = __builtin_amdgcn_mfma_f32_16x16x32_bf16(
                        af[mi], bfv[nj], acc[mi][nj], 0, 0, 0);
        }
        __syncthreads();
    }
    float* pp = part + ((size_t)s * bhTot + bh) * 4096;
#pragma unroll
    for (int mi = 0; mi < 2; ++mi)
#pragma unroll
        for (int nj = 0; nj < 2; ++nj) {
            int e = wc * 32 + nj * 16 + r16;
#pragma unroll
            for (int r = 0; r < 4; ++r) {
                int d = wr * 32 + mi * 16 + kg * 4 + r;
                pp[d * 64 + e] = acc[mi][nj][r];
            }
        }
}

// ---------------------------------------------------------------------------
// Reduce partials, scale, softmax over e. One wave per (bh,d) row.
// Writes P TRANSPOSED: PT[bh][e*64+d].
// ---------------------------------------------------------------------------
__global__ __launch_bounds__(64) void softmax_kernel(
    const float* __restrict__ part, float* __restrict__ PT, int bhTot)
{
    int row = blockIdx.x;                 // bh*64 + d
    int e = threadIdx.x;
    size_t base = (size_t)row * 64 + e;
    float val = 0.f;
#pragma unroll
    for (int s = 0; s < SPLIT; ++s) val += part[(size_t)s * bhTot * 4096 + base];
    val *= 0.125f;                        // hd^-0.5
    float m = val;
#pragma unroll
    for (int off = 32; off > 0; off >>= 1) m = fmaxf(m, __shfl_xor(m, off));
    float ex = expf(val - m);
    float sum = ex;
#pragma unroll
    for (int off = 32; off > 0; off >>= 1) sum += __shfl_xor(sum, off);
    PT[(size_t)(row >> 6) * 4096 + (size_t)e * 64 + (row & 63)] = ex / sum;
}

// ---------------------------------------------------------------------------
// outA[b_l][d][h][n] = sum_e PT[e][d] * v[b_l][h*64+e][n]   (bf16 out)
// 128-px tile per block: PT (16KB) staged once serves 2x the output.
// ---------------------------------------------------------------------------
__global__ __launch_bounds__(256) void pv_kernel(
    const bf16* __restrict__ v, const float* __restrict__ PT,
    bf16* __restrict__ outA)
{
    __shared__ float pts[4096];           // PT[e][d] 16KB
    __shared__ bf16 vs[64 * 128];         // vs[e][n] 16KB
    int bid = blockIdx.x;                 // bhTot*25
    int nt = bid % 25; int bh = bid / 25;
    int h = bh % NH, b_l = bh / NH;
    int t = threadIdx.x;
    int nbase = nt * 128;                 // nt=24 tile is partial (3072..3135)
    const float* ptg = PT + (size_t)bh * 4096;
#pragma unroll
    for (int i = 0; i < 4; ++i)
        load_lds16(ptg + i * 1024 + t * 4, (char*)pts + i * 4096 + t * 16);
    const bf16* vb = v + ((size_t)b_l * C_ + h * HD) * N_;
#pragma unroll
    for (int i = 0; i < 4; ++i) {
        int row = i * 16 + (t >> 4);      // e row 0..63
        int n = nbase + (t & 15) * 8;
        if (n > N_ - 8) n = N_ - 8;       // clamp source (dup cols unused)
        load_lds16(vb + (size_t)row * N_ + n,
                   (char*)vs + i * 4096 + (t >> 4) * 256 + (t & 15) * 16);
    }
    __syncthreads();

    int ng = t & 31, dg = t >> 5;         // n-sub = ng*4 (0..127), d0 = dg*8
    float acc[8][4] = {};
#pragma unroll 8
    for (int e = 0; e < 64; ++e) {
        float4 p0 = *(const float4*)&pts[e * 64 + dg * 8];
        float4 p1 = *(const float4*)&pts[e * 64 + dg * 8 + 4];
        ushort4 vv = *(const ushort4*)&vs[e * 128 + ng * 4];
        float v0 = bf2f(vv.x), v1 = bf2f(vv.y), v2 = bf2f(vv.z), v3 = bf2f(vv.w);
        float p8[8] = {p0.x, p0.y, p0.z, p0.w, p1.x, p1.y, p1.z, p1.w};
#pragma unroll
        for (int i = 0; i < 8; ++i) {
            acc[i][0] = fmaf(p8[i], v0, acc[i][0]);
            acc[i][1] = fmaf(p8[i], v1, acc[i][1]);
            acc[i][2] = fmaf(p8[i], v2, acc[i][2]);
            acc[i][3] = fmaf(p8[i], v3, acc[i][3]);
        }
    }
    if (nbase + ng * 4 < N_) {            // 4-aligned, N_ % 4 == 0
        bf16* op = outA + (size_t)b_l * (C_*N_) + (size_t)h * N_ + nbase + ng * 4;
#pragma unroll
        for (int i = 0; i < 8; ++i) {
            ushort4 r4;
            unsigned short* rr = (unsigned short*)&r4;
            rr[0] = f2bf(acc[i][0]); rr[1] = f2bf(acc[i][1]);
            rr[2] = f2bf(acc[i][2]); rr[3] = f2bf(acc[i][3]);
            *(ushort4*)(op + (size_t)(dg * 8 + i) * (NH*N_)) = r4;
        }
    }
}

// ---------------------------------------------------------------------------
// Convert projection weights f32 -> bf16 (512x512).
// ---------------------------------------------------------------------------
__global__ __launch_bounds__(256) void wconv_kernel(
    const float* __restrict__ w, bf16* __restrict__ wb)
{
    int i = blockIdx.x * 256 + threadIdx.x;   // 262144 total
    wb[i] = f2bf(w[i]);
}

// ---------------------------------------------------------------------------
// MFMA projection, 8 waves, tile 128(co) x 256(n), single-buffered LDS
// (48KB), XCD-chunked swizzle with mt fastest.
//   out[b0+b_l][co][n] = sum_c Wb[co][c]*A[b_l][n][c] + pb[co]
// ---------------------------------------------------------------------------
__global__ __launch_bounds__(512) void proj_mfma_kernel(
    const bf16* __restrict__ A, const bf16* __restrict__ Wb,
    const float* __restrict__ bias, float* __restrict__ out, int b0, int nwg)
{
    __shared__ bf16 Ws_s[128 * 64];       // 16 KB
    __shared__ bf16 As_s[256 * 64];       // 32 KB
    int bid = blockIdx.x;                 // nwg = nb*52, nwg % 8 == 0
    int cpx = nwg >> 3;                   // chunk per XCD (104: % 4 == 0)
    int swz = (bid & 7) * cpx + (bid >> 3);
    int b_l = swz / 52; int rem = swz % 52;
    int nt = rem >> 2, mt = rem & 3;      // mt fastest: A-quad on one XCD
    int m0 = mt * 128, n0 = nt * 256;     // nt in 0..12
    int t = threadIdx.x;
    int w = t >> 6, l = t & 63;
    int r16 = l & 15, kg = l >> 4;        // frag row / k-group
    int wr = w >> 2, wc = w & 3;          // wave quadrant: 2 co x 4 n
    const bf16* Ab = A + (size_t)b_l * N_ * C_;
    int srow = t >> 3;                    // staging row within 64-row chunk
    int colp = ((t & 7) ^ (srow & 7)) * 8;// pre-swizzled k-element offset

    f32x4 acc[4][4];
#pragma unroll
    for (int i = 0; i < 4; ++i)
#pragma unroll
        for (int j = 0; j < 4; ++j) acc[i][j] = (f32x4){0.f, 0.f, 0.f, 0.f};

    for (int k0 = 0; k0 < C_; k0 += 64) {
#pragma unroll
        for (int i = 0; i < 2; ++i) {
            int row = i * 64 + srow;
            load_lds16(Wb + (size_t)(m0 + row) * C_ + k0 + colp,
                       (char*)Ws_s + i * 8192 + t * 16);
        }
#pragma unroll
        for (int i = 0; i < 4; ++i) {
            int row = i * 64 + srow;
            int nn = n0 + row; if (nn >= N_) nn = N_ - 1;
            load_lds16(Ab + (size_t)nn * C_ + k0 + colp,
                       (char*)As_s + i * 8192 + t * 16);
        }
        __syncthreads();
#pragma unroll
        for (int ks = 0; ks < 2; ++ks) {
            short8 af[4], bfv[4];
#pragma unroll
            for (int mi = 0; mi < 4; ++mi) {
                int row = wr * 64 + mi * 16 + r16;
                int off = row * 128 + ((ks * 64 + kg * 16) ^ ((row & 7) << 4));
                af[mi] = *(const short8*)((const char*)Ws_s + off);
            }
#pragma unroll
            for (int nj = 0; nj < 4; ++nj) {
                int row = wc * 64 + nj * 16 + r16;
                int off = row * 128 + ((ks * 64 + kg * 16) ^ ((row & 7) << 4));
                bfv[nj] = *(const short8*)((const char*)As_s + off);
            }
#pragma unroll
            for (int mi = 0; mi < 4; ++mi)
#pragma unroll
                for (int nj = 0; nj < 4; ++nj)
                    acc[mi][nj] = __builtin_amdgcn_mfma_f32_16x16x32_bf16(
                        af[mi], bfv[nj], acc[mi][nj], 0, 0, 0);
        }
        __syncthreads();
    }
    float* ob = out + ((size_t)(b0 + b_l) * C_) * N_;
#pragma unroll
    for (int mi = 0; mi < 4; ++mi) {
        int cobase = m0 + wr * 64 + mi * 16 + kg * 4;
#pragma unroll
        for (int r = 0; r < 4; ++r) {
            int co = cobase + r;
            float bi = bias[co];
#pragma unroll
            for (int nj = 0; nj < 4; ++nj) {
                int n = n0 + wc * 64 + nj * 16 + r16;
                if (n < N_) ob[(size_t)co * N_ + n] = acc[mi][nj][r] + bi;
            }
        }
    }
}

extern "C" void kernel_launch(void* const* d_in, const int* in_sizes, int n_in,
                              void* d_out, int out_size, void* d_ws, size_t ws_size,
                              hipStream_t stream) {
    const float* x     = (const float*)d_in[0];
    const float* cw    = (const float*)d_in[1];
    const float* gamma = (const float*)d_in[2];
    const float* beta  = (const float*)d_in[3];
    const float* mean  = (const float*)d_in[4];
    const float* var   = (const float*)d_in[5];
    const float* pw    = (const float*)d_in[6];
    const float* pb    = (const float*)d_in[7];
    float* out = (float*)d_out;
    char* wsp = (char*)d_ws;

    const size_t W_B = (size_t)C_ * C_ * sizeof(bf16);              // 524,288

    // Single-pass (all 16 batches) if workspace allows; else two passes of 8.
    size_t qk16   = (size_t)16 * 2 * C_ * N_ * sizeof(bf16);        // 102.8 MB
    size_t v16    = (size_t)16 * C_ * N_ * sizeof(bf16);            //  51.4 MB
    size_t part16 = (size_t)SPLIT * 16 * NH * 4096 * 4;             //  14.7 MB
    size_t pt16   = (size_t)16 * NH * 4096 * 4;                     //   2.1 MB

    int nbs[2]; int ngroups;
    if (ws_size >= qk16 + v16 + part16 + pt16 + W_B) {
        ngroups = 1; nbs[0] = 16;
    } else {
        ngroups = 2; nbs[0] = 8; nbs[1] = 8;
    }

    int b0 = 0;
    for (int gi = 0; gi < ngroups; ++gi) {
        int nb = nbs[gi];
        size_t QK_B   = (size_t)nb * 2 * C_ * N_ * sizeof(bf16);
        size_t V_B    = (size_t)nb * C_ * N_ * sizeof(bf16);
        size_t PART_B = (size_t)SPLIT * nb * NH * 4096 * 4;
        size_t PT_B   = (size_t)nb * NH * 4096 * 4;
        bf16*  qk   = (bf16*)wsp;
        bf16*  v    = (bf16*)(wsp + QK_B);
        float* part = (float*)(wsp + QK_B + V_B);
        float* PT   = (float*)(wsp + QK_B + V_B + PART_B);
        bf16*  Wbf  = (bf16*)(wsp + QK_B + V_B + PART_B + PT_B);
        bf16*  outA = qk;                  // reuse q,k region after gram
        int bhTot = nb * NH;

        if (gi == 0)
            wconv_kernel<<<(C_ * C_) / 256, 256, 0, stream>>>(pw, Wbf);

        conv_bn_kernel<<<nb * C_, 448, 0, stream>>>(
            x, cw, gamma, beta, mean, var, qk, v, b0);
        gram_mfma_kernel<<<bhTot * SPLIT, 256, 0, stream>>>(qk, part, bhTot);
        softmax_kernel<<<bhTot * 64, 64, 0, stream>>>(part, PT, bhTot);
        pv_kernel<<<bhTot * 25, 256, 0, stream>>>(v, PT, outA);
        proj_mfma_kernel<<<nb * 52, 512, 0, stream>>>(outA, Wbf, pb, out, b0, nb * 52);
        b0 += nb;
    }
}

// Round 18
// 178.344 us; speedup vs baseline: 1.3452x; 1.0214x over previous
//
#include <hip/hip_runtime.h>
#include <hip/hip_bf16.h>
#include <math.h>

#define B_ 16
#define C_ 512
#define H_ 56
#define W_ 56
#define N_ 3136          // H_*W_ = 49*64
#define NH 8
#define HD 64
#define SPLIT 7          // n-split for gram; 3136/7 = 448
#define XPAD 58          // padded x-row stride in floats (bank-spread)

typedef unsigned short bf16;
typedef __attribute__((ext_vector_type(8))) short short8;
typedef __attribute__((ext_vector_type(4))) float f32x4;

__device__ inline float bf2f(unsigned short u) {
    union { unsigned int i; float f; } v; v.i = ((unsigned int)u) << 16; return v.f;
}
// Compiler-native conversion (RNE): pairs get packed into v_cvt_pk_bf16_f32.
__device__ inline unsigned short f2bf(float f) {
    union { __hip_bfloat16 h; unsigned short u; } v;
    v.h = __float2bfloat16(f);
    return v.u;
}

// async global->LDS, 16B per lane, linear dest (wave-uniform base + lane*16)
__device__ inline void load_lds16(const void* g, void* l) {
    __builtin_amdgcn_global_load_lds(
        (const __attribute__((address_space(1))) void*)g,
        (__attribute__((address_space(3))) void*)l, 16, 0, 0);
}

// ---------------------------------------------------------------------------
// Depthwise 3x3 conv + BN. Block = (b_l, ic). x-plane reg-staged into PADDED
// LDS (row stride 58 floats): read bank base (26*y2+8*xt)%32 spreads ~4-way
// vs 16-way for the linear layout (rule: gload_lds forces linear dest, so we
// stage through registers to get the padded layout).
// ---------------------------------------------------------------------------
__global__ __launch_bounds__(448) void conv_bn_kernel(
    const float* __restrict__ x, const float* __restrict__ cw,
    const float* __restrict__ gamma, const float* __restrict__ beta,
    const float* __restrict__ mean, const float* __restrict__ var,
    bf16* __restrict__ qkdst, bf16* __restrict__ vdst, int b0)
{
    __shared__ float xs[H_ * XPAD];       // 56*58*4 = 12,992 B
    int bid = blockIdx.x;                 // nb*C_
    int ic = bid & 511; int b_l = bid >> 9;
    int b = b0 + b_l;
    const float* xin = x + ((size_t)b * C_ + ic) * N_;
    int t = threadIdx.x;

    // stage: 784 16B chunks; thread t handles chunk t (+ chunk t+448 if any)
    float4 v0 = *(const float4*)(xin + (size_t)t * 4);
    float4 v1;
    if (t < 336) v1 = *(const float4*)(xin + (size_t)(t + 448) * 4);
    {
        int r = t / 14, cc = t - r * 14;
        float* p = &xs[r * XPAD + cc * 4];
        *(float2*)(p + 0) = make_float2(v0.x, v0.y);
        *(float2*)(p + 2) = make_float2(v0.z, v0.w);
    }
    if (t < 336) {
        int c2 = t + 448;
        int r = c2 / 14, cc = c2 - r * 14;
        float* p = &xs[r * XPAD + cc * 4];
        *(float2*)(p + 0) = make_float2(v1.x, v1.y);
        *(float2*)(p + 2) = make_float2(v1.z, v1.w);
    }

    // block-uniform filter + BN constants (scalar loads)
    float w9[3][9], inv3[3], bias3[3];
#pragma unroll
    for (int ft = 0; ft < 3; ++ft) {
        int o = ic * 3 + ft;
#pragma unroll
        for (int k = 0; k < 9; ++k) w9[ft][k] = cw[o * 9 + k];
        float iv = gamma[o] * rsqrtf(var[o] + 1e-5f);
        inv3[ft] = iv;
        bias3[ft] = fmaf(-mean[o], iv, beta[o]);
    }
    __syncthreads();

    if (t < 392) {
        int yy = t / 7;
        int xx0 = (t - yy * 7) * 8;
        int n0 = t * 8;                   // == yy*56 + xx0
        float vin[3][10];
#pragma unroll
        for (int dy = 0; dy < 3; ++dy) {
            int y2 = yy + dy - 1;
            if (y2 >= 0 && y2 < H_) {
                const float* rp = &xs[y2 * XPAD + xx0];
#pragma unroll
                for (int j = 0; j < 8; ++j) vin[dy][j + 1] = rp[j];
                vin[dy][0] = (xx0 > 0)  ? rp[-1] : 0.f;
                vin[dy][9] = (xx0 < 48) ? rp[8]  : 0.f;
            } else {
#pragma unroll
                for (int j = 0; j < 10; ++j) vin[dy][j] = 0.f;
            }
        }
#pragma unroll
        for (int ft = 0; ft < 3; ++ft) {
            int o = ic * 3 + ft;          // uniform
            int s = o >> 9;               // uniform
            int c = o & 511;
            float r[8];
#pragma unroll
            for (int j = 0; j < 8; ++j) {
                float acc = 0.f;
#pragma unroll
                for (int ky = 0; ky < 3; ++ky)
#pragma unroll
                    for (int kx = 0; kx < 3; ++kx)
                        acc = fmaf(vin[ky][j + kx], w9[ft][ky*3+kx], acc);
                r[j] = fmaf(acc, inv3[ft], bias3[ft]);
            }
            short8 r8;
#pragma unroll
            for (int j = 0; j < 8; ++j) r8[j] = (short)f2bf(r[j]);
            bf16* dst = (s < 2)
                ? qkdst + (((size_t)b_l * 2 + s) * C_ + c) * N_
                : vdst + ((size_t)b_l * C_ + c) * N_;
            *(short8*)(dst + n0) = r8;
        }
    }
}

// ---------------------------------------------------------------------------
// Gram partials via MFMA (T2 swizzle + gload_lds):
//   part[s][bh][d*64+e] = sum_{n in split s} q[d,n]*k[e,n]
// ---------------------------------------------------------------------------
__global__ __launch_bounds__(256) void gram_mfma_kernel(
    const bf16* __restrict__ qk, float* __restrict__ part, int bhTot)
{
    __shared__ bf16 qs[64 * 64];
    __shared__ bf16 ks[64 * 64];
    int bid = blockIdx.x;                 // bhTot*SPLIT
    int s = bid % SPLIT; int bh = bid / SPLIT;
    int h = bh % NH; int b_l = bh / NH;
    const bf16* qp = qk + (((size_t)b_l * 2 + 0) * C_ + h * HD) * N_;
    const bf16* kp = qk + (((size_t)b_l * 2 + 1) * C_ + h * HD) * N_;
    int t = threadIdx.x;
    int w = t >> 6, l = t & 63;
    int r16 = l & 15, kg = l >> 4;
    int wr = w >> 1, wc = w & 1;
    int rsub = l >> 3;
    int colp = ((l & 7) ^ rsub) * 8;      // pre-swizzled n-element offset
    int n0 = s * (N_ / SPLIT);

    f32x4 acc[2][2];
#pragma unroll
    for (int i = 0; i < 2; ++i)
#pragma unroll
        for (int j = 0; j < 2; ++j) acc[i][j] = (f32x4){0.f, 0.f, 0.f, 0.f};

    for (int nc = 0; nc < N_ / SPLIT; nc += 64) {
        int nb = n0 + nc;
#pragma unroll
        for (int i = 0; i < 2; ++i) {
            int row = i * 32 + w * 8 + rsub;
            load_lds16(qp + (size_t)row * N_ + nb + colp, (char*)qs + i * 4096 + t * 16);
            load_lds16(kp + (size_t)row * N_ + nb + colp, (char*)ks + i * 4096 + t * 16);
        }
        __syncthreads();
#pragma unroll
        for (int ksb = 0; ksb < 2; ++ksb) {
            short8 af[2], bfv[2];
#pragma unroll
            for (int mi = 0; mi < 2; ++mi) {
                int row = wr * 32 + mi * 16 + r16;
                int off = row * 128 + ((ksb * 64 + kg * 16) ^ ((row & 7) << 4));
                af[mi] = *(const short8*)((const char*)qs + off);
            }
#pragma unroll
            for (int nj = 0; nj < 2; ++nj) {
                int row = wc * 32 + nj * 16 + r16;
                int off = row * 128 + ((ksb * 64 + kg * 16) ^ ((row & 7) << 4));
                bfv[nj] = *(const short8*)((const char*)ks + off);
            }
#pragma unroll
            for (int mi = 0; mi < 2; ++mi)
#pragma unroll
                for (int nj = 0; nj < 2; ++nj)
                    acc[mi][nj] = __builtin_amdgcn_mfma_f32_16x16x32_bf16(
                        af[mi], bfv[nj], acc[mi][nj], 0, 0, 0);
        }
        __syncthreads();
    }
    float* pp = part + ((size_t)s * bhTot + bh) * 4096;
#pragma unroll
    for (int mi = 0; mi < 2; ++mi)
#pragma unroll
        for (int nj = 0; nj < 2; ++nj) {
            int e = wc * 32 + nj * 16 + r16;
#pragma unroll
            for (int r = 0; r < 4; ++r) {
                int d = wr * 32 + mi * 16 + kg * 4 + r;
                pp[d * 64 + e] = acc[mi][nj][r];
            }
        }
}

// ---------------------------------------------------------------------------
// Reduce partials, scale, softmax over e. One wave per (bh,d) row.
// Writes P TRANSPOSED: PT[bh][e*64+d].
// ---------------------------------------------------------------------------
__global__ __launch_bounds__(64) void softmax_kernel(
    const float* __restrict__ part, float* __restrict__ PT, int bhTot)
{
    int row = blockIdx.x;                 // bh*64 + d
    int e = threadIdx.x;
    size_t base = (size_t)row * 64 + e;
    float val = 0.f;
#pragma unroll
    for (int s = 0; s < SPLIT; ++s) val += part[(size_t)s * bhTot * 4096 + base];
    val *= 0.125f;                        // hd^-0.5
    float m = val;
#pragma unroll
    for (int off = 32; off > 0; off >>= 1) m = fmaxf(m, __shfl_xor(m, off));
    float ex = expf(val - m);
    float sum = ex;
#pragma unroll
    for (int off = 32; off > 0; off >>= 1) sum += __shfl_xor(sum, off);
    PT[(size_t)(row >> 6) * 4096 + (size_t)e * 64 + (row & 63)] = ex / sum;
}

// ---------------------------------------------------------------------------
// outA[b_l][d][h][n] = sum_e PT[e][d] * v[b_l][h*64+e][n]   (bf16 out)
// 128-px tile per block: PT (16KB) staged once serves 2x the output.
// ---------------------------------------------------------------------------
__global__ __launch_bounds__(256) void pv_kernel(
    const bf16* __restrict__ v, const float* __restrict__ PT,
    bf16* __restrict__ outA)
{
    __shared__ float pts[4096];           // PT[e][d] 16KB
    __shared__ bf16 vs[64 * 128];         // vs[e][n] 16KB
    int bid = blockIdx.x;                 // bhTot*25
    int nt = bid % 25; int bh = bid / 25;
    int h = bh % NH, b_l = bh / NH;
    int t = threadIdx.x;
    int nbase = nt * 128;                 // nt=24 tile is partial (3072..3135)
    const float* ptg = PT + (size_t)bh * 4096;
#pragma unroll
    for (int i = 0; i < 4; ++i)
        load_lds16(ptg + i * 1024 + t * 4, (char*)pts + i * 4096 + t * 16);
    const bf16* vb = v + ((size_t)b_l * C_ + h * HD) * N_;
#pragma unroll
    for (int i = 0; i < 4; ++i) {
        int row = i * 16 + (t >> 4);      // e row 0..63
        int n = nbase + (t & 15) * 8;
        if (n > N_ - 8) n = N_ - 8;       // clamp source (dup cols unused)
        load_lds16(vb + (size_t)row * N_ + n,
                   (char*)vs + i * 4096 + (t >> 4) * 256 + (t & 15) * 16);
    }
    __syncthreads();

    int ng = t & 31, dg = t >> 5;         // n-sub = ng*4 (0..127), d0 = dg*8
    float acc[8][4] = {};
#pragma unroll 8
    for (int e = 0; e < 64; ++e) {
        float4 p0 = *(const float4*)&pts[e * 64 + dg * 8];
        float4 p1 = *(const float4*)&pts[e * 64 + dg * 8 + 4];
        ushort4 vv = *(const ushort4*)&vs[e * 128 + ng * 4];
        float v0 = bf2f(vv.x), v1 = bf2f(vv.y), v2 = bf2f(vv.z), v3 = bf2f(vv.w);
        float p8[8] = {p0.x, p0.y, p0.z, p0.w, p1.x, p1.y, p1.z, p1.w};
#pragma unroll
        for (int i = 0; i < 8; ++i) {
            acc[i][0] = fmaf(p8[i], v0, acc[i][0]);
            acc[i][1] = fmaf(p8[i], v1, acc[i][1]);
            acc[i][2] = fmaf(p8[i], v2, acc[i][2]);
            acc[i][3] = fmaf(p8[i], v3, acc[i][3]);
        }
    }
    if (nbase + ng * 4 < N_) {            // 4-aligned, N_ % 4 == 0
        bf16* op = outA + (size_t)b_l * (C_*N_) + (size_t)h * N_ + nbase + ng * 4;
#pragma unroll
        for (int i = 0; i < 8; ++i) {
            ushort4 r4;
            unsigned short* rr = (unsigned short*)&r4;
            rr[0] = f2bf(acc[i][0]); rr[1] = f2bf(acc[i][1]);
            rr[2] = f2bf(acc[i][2]); rr[3] = f2bf(acc[i][3]);
            *(ushort4*)(op + (size_t)(dg * 8 + i) * (NH*N_)) = r4;
        }
    }
}

// ---------------------------------------------------------------------------
// Convert projection weights f32 -> bf16 (512x512).
// ---------------------------------------------------------------------------
__global__ __launch_bounds__(256) void wconv_kernel(
    const float* __restrict__ w, bf16* __restrict__ wb)
{
    int i = blockIdx.x * 256 + threadIdx.x;   // 262144 total
    wb[i] = f2bf(w[i]);
}

// ---------------------------------------------------------------------------
// MFMA projection, 8 waves, tile 128(co) x 256(n), single-buffered LDS
// (48KB), XCD-chunked swizzle with mt fastest.
//   out[b0+b_l][co][n] = sum_c Wb[co][c]*A[b_l][n][c] + pb[co]
// ---------------------------------------------------------------------------
__global__ __launch_bounds__(512) void proj_mfma_kernel(
    const bf16* __restrict__ A, const bf16* __restrict__ Wb,
    const float* __restrict__ bias, float* __restrict__ out, int b0, int nwg)
{
    __shared__ bf16 Ws_s[128 * 64];       // 16 KB
    __shared__ bf16 As_s[256 * 64];       // 32 KB
    int bid = blockIdx.x;                 // nwg = nb*52, nwg % 8 == 0
    int cpx = nwg >> 3;                   // chunk per XCD (104: % 4 == 0)
    int swz = (bid & 7) * cpx + (bid >> 3);
    int b_l = swz / 52; int rem = swz % 52;
    int nt = rem >> 2, mt = rem & 3;      // mt fastest: A-quad on one XCD
    int m0 = mt * 128, n0 = nt * 256;     // nt in 0..12
    int t = threadIdx.x;
    int w = t >> 6, l = t & 63;
    int r16 = l & 15, kg = l >> 4;        // frag row / k-group
    int wr = w >> 2, wc = w & 3;          // wave quadrant: 2 co x 4 n
    const bf16* Ab = A + (size_t)b_l * N_ * C_;
    int srow = t >> 3;                    // staging row within 64-row chunk
    int colp = ((t & 7) ^ (srow & 7)) * 8;// pre-swizzled k-element offset

    f32x4 acc[4][4];
#pragma unroll
    for (int i = 0; i < 4; ++i)
#pragma unroll
        for (int j = 0; j < 4; ++j) acc[i][j] = (f32x4){0.f, 0.f, 0.f, 0.f};

    for (int k0 = 0; k0 < C_; k0 += 64) {
#pragma unroll
        for (int i = 0; i < 2; ++i) {
            int row = i * 64 + srow;
            load_lds16(Wb + (size_t)(m0 + row) * C_ + k0 + colp,
                       (char*)Ws_s + i * 8192 + t * 16);
        }
#pragma unroll
        for (int i = 0; i < 4; ++i) {
            int row = i * 64 + srow;
            int nn = n0 + row; if (nn >= N_) nn = N_ - 1;
            load_lds16(Ab + (size_t)nn * C_ + k0 + colp,
                       (char*)As_s + i * 8192 + t * 16);
        }
        __syncthreads();
#pragma unroll
        for (int ks = 0; ks < 2; ++ks) {
            short8 af[4], bfv[4];
#pragma unroll
            for (int mi = 0; mi < 4; ++mi) {
                int row = wr * 64 + mi * 16 + r16;
                int off = row * 128 + ((ks * 64 + kg * 16) ^ ((row & 7) << 4));
                af[mi] = *(const short8*)((const char*)Ws_s + off);
            }
#pragma unroll
            for (int nj = 0; nj < 4; ++nj) {
                int row = wc * 64 + nj * 16 + r16;
                int off = row * 128 + ((ks * 64 + kg * 16) ^ ((row & 7) << 4));
                bfv[nj] = *(const short8*)((const char*)As_s + off);
            }
#pragma unroll
            for (int mi = 0; mi < 4; ++mi)
#pragma unroll
                for (int nj = 0; nj < 4; ++nj)
                    acc[mi][nj] = __builtin_amdgcn_mfma_f32_16x16x32_bf16(
                        af[mi], bfv[nj], acc[mi][nj], 0, 0, 0);
        }
        __syncthreads();
    }
    float* ob = out + ((size_t)(b0 + b_l) * C_) * N_;
#pragma unroll
    for (int mi = 0; mi < 4; ++mi) {
        int cobase = m0 + wr * 64 + mi * 16 + kg * 4;
#pragma unroll
        for (int r = 0; r < 4; ++r) {
            int co = cobase + r;
            float bi = bias[co];
#pragma unroll
            for (int nj = 0; nj < 4; ++nj) {
                int n = n0 + wc * 64 + nj * 16 + r16;
                if (n < N_) ob[(size_t)co * N_ + n] = acc[mi][nj][r] + bi;
            }
        }
    }
}

extern "C" void kernel_launch(void* const* d_in, const int* in_sizes, int n_in,
                              void* d_out, int out_size, void* d_ws, size_t ws_size,
                              hipStream_t stream) {
    const float* x     = (const float*)d_in[0];
    const float* cw    = (const float*)d_in[1];
    const float* gamma = (const float*)d_in[2];
    const float* beta  = (const float*)d_in[3];
    const float* mean  = (const float*)d_in[4];
    const float* var   = (const float*)d_in[5];
    const float* pw    = (const float*)d_in[6];
    const float* pb    = (const float*)d_in[7];
    float* out = (float*)d_out;
    char* wsp = (char*)d_ws;

    const size_t W_B = (size_t)C_ * C_ * sizeof(bf16);              // 524,288

    // Single-pass (all 16 batches) if workspace allows; else two passes of 8.
    size_t qk16   = (size_t)16 * 2 * C_ * N_ * sizeof(bf16);        // 102.8 MB
    size_t v16    = (size_t)16 * C_ * N_ * sizeof(bf16);            //  51.4 MB
    size_t part16 = (size_t)SPLIT * 16 * NH * 4096 * 4;             //  14.7 MB
    size_t pt16   = (size_t)16 * NH * 4096 * 4;                     //   2.1 MB

    int nbs[2]; int ngroups;
    if (ws_size >= qk16 + v16 + part16 + pt16 + W_B) {
        ngroups = 1; nbs[0] = 16;
    } else {
        ngroups = 2; nbs[0] = 8; nbs[1] = 8;
    }

    int b0 = 0;
    for (int gi = 0; gi < ngroups; ++gi) {
        int nb = nbs[gi];
        size_t QK_B   = (size_t)nb * 2 * C_ * N_ * sizeof(bf16);
        size_t V_B    = (size_t)nb * C_ * N_ * sizeof(bf16);
        size_t PART_B = (size_t)SPLIT * nb * NH * 4096 * 4;
        size_t PT_B   = (size_t)nb * NH * 4096 * 4;
        bf16*  qk   = (bf16*)wsp;
        bf16*  v    = (bf16*)(wsp + QK_B);
        float* part = (float*)(wsp + QK_B + V_B);
        float* PT   = (float*)(wsp + QK_B + V_B + PART_B);
        bf16*  Wbf  = (bf16*)(wsp + QK_B + V_B + PART_B + PT_B);
        bf16*  outA = qk;                  // reuse q,k region after gram
        int bhTot = nb * NH;

        if (gi == 0)
            wconv_kernel<<<(C_ * C_) / 256, 256, 0, stream>>>(pw, Wbf);

        conv_bn_kernel<<<nb * C_, 448, 0, stream>>>(
            x, cw, gamma, beta, mean, var, qk, v, b0);
        gram_mfma_kernel<<<bhTot * SPLIT, 256, 0, stream>>>(qk, part, bhTot);
        softmax_kernel<<<bhTot * 64, 64, 0, stream>>>(part, PT, bhTot);
        pv_kernel<<<bhTot * 25, 256, 0, stream>>>(v, PT, outA);
        proj_mfma_kernel<<<nb * 52, 512, 0, stream>>>(outA, Wbf, pb, out, b0, nb * 52);
        b0 += nb;
    }
}